// Round 2
// baseline (4157.370 us; speedup 1.0000x reference)
//
#include <hip/hip_runtime.h>
#include <hip/hip_bf16.h>
#include <math.h>

// ---------------- problem constants ----------------
constexpr int Bb = 2, Ss = 2048, Tt = 4096;
constexpr int HID = 512, DQn = 256, DKVn = 128, RHn = 32, NHn = 8, UHn = 64, QDn = 96;
constexpr int INTERn = 256, NEn = 16, TKn = 4;
constexpr float EPSf = 1.1920929e-07f;

// ---------------- workspace layout (float elements) ----------------
constexpr size_t OFF_XN   = 0;                                  // T*512
constexpr size_t OFF_CQ   = OFF_XN   + (size_t)Tt * HID;        // T*256
constexpr size_t OFF_CKV  = OFF_CQ   + (size_t)Tt * DQn;        // T*160
constexpr size_t OFF_CQN  = OFF_CKV  + (size_t)Tt * 160;        // T*256
constexpr size_t OFF_CKVN = OFF_CQN  + (size_t)Tt * DQn;        // T*128
constexpr size_t OFF_QCR  = OFF_CKVN + (size_t)Tt * DKVn;       // T*768
constexpr size_t OFF_KV   = OFF_QCR  + (size_t)Tt * 768;        // T*1024
constexpr size_t OFF_QB   = OFF_KV   + (size_t)Tt * 1024;       // 16*2048*96
constexpr size_t OFF_KB   = OFF_QB   + (size_t)16 * 2048 * 96;
constexpr size_t OFF_VB   = OFF_KB   + (size_t)16 * 2048 * 96;  // 16*2048*64
constexpr size_t OFF_AO   = OFF_VB   + (size_t)16 * 2048 * 64;  // T*512
constexpr size_t OFF_R2   = OFF_AO   + (size_t)Tt * HID;
constexpr size_t OFF_XN2  = OFF_R2   + (size_t)Tt * HID;
constexpr size_t OFF_G    = OFF_XN2  + (size_t)Tt * HID;        // T*256
constexpr size_t OFF_U    = OFF_G    + (size_t)Tt * INTERn;
constexpr size_t OFF_OACC = OFF_U    + (size_t)Tt * INTERn;     // T*512
constexpr size_t OFF_EACT = OFF_OACC + (size_t)Tt * HID;        // T*4*256
constexpr size_t OFF_EWT  = OFF_EACT + (size_t)Tt * 4 * INTERn; // 16*4096
constexpr size_t OFF_ECNT = OFF_EWT  + (size_t)NEn * Tt;        // 16 ints (64 floats pad)
constexpr size_t OFF_ETOK = OFF_ECNT + 64;                      // 16*4096 ints

// ---------------- RMSNorm (f32 in -> f32 out, strided) ----------------
__global__ void k_rms(const float* __restrict__ in, int inStride,
                      const float* __restrict__ w,
                      float* __restrict__ out, int outStride, int D) {
    int row = blockIdx.x, tid = threadIdx.x;
    __shared__ float xs[512];
    __shared__ float red[256];
    const float* ip = in + (size_t)row * inStride;
    float ss = 0.f;
    for (int i = tid; i < D; i += 256) { float v = ip[i]; xs[i] = v; ss += v * v; }
    red[tid] = ss; __syncthreads();
    for (int s = 128; s > 0; s >>= 1) { if (tid < s) red[tid] += red[tid + s]; __syncthreads(); }
    float sc = rsqrtf(red[0] / (float)D + EPSf);
    float* op = out + (size_t)row * outStride;
    for (int i = tid; i < D; i += 256) op[i] = xs[i] * sc * w[i];
}

// ---------------- generic tiled GEMM: C(f32) = A(f32) @ B(f32) [+ add f32] ----------------
// EPI: 0 none, 1 add f32 residual
template <int EPI>
__global__ __launch_bounds__(256)
void k_gemm(const float* __restrict__ A, int lda,
            const float* __restrict__ Bw, int ldb,
            float* __restrict__ C, int ldc,
            int M, int N, int K,
            const float* __restrict__ addp, int ldadd) {
    __shared__ float As[64][17];
    __shared__ float Bs[16][64];
    int tid = threadIdx.x;
    int tm = tid & 15, tn = tid >> 4;
    int m0 = blockIdx.y * 64, n0 = blockIdx.x * 64;
    float acc[4][4] = {};
    for (int k0 = 0; k0 < K; k0 += 16) {
#pragma unroll
        for (int i = 0; i < 4; ++i) {
            int idx = i * 256 + tid;
            int m = idx >> 4, k = idx & 15;
            int gm = m0 + m;
            As[m][k] = (gm < M) ? A[(size_t)gm * lda + k0 + k] : 0.f;
        }
#pragma unroll
        for (int i = 0; i < 4; ++i) {
            int idx = i * 256 + tid;
            int k = idx >> 6, n = idx & 63;
            int gn = n0 + n;
            Bs[k][n] = (gn < N) ? Bw[(size_t)(k0 + k) * ldb + gn] : 0.f;
        }
        __syncthreads();
#pragma unroll
        for (int k = 0; k < 16; ++k) {
            float av[4] = { As[tm][k], As[tm + 16][k], As[tm + 32][k], As[tm + 48][k] };
            float4 b4 = *(const float4*)&Bs[k][tn * 4];
            float bv[4] = { b4.x, b4.y, b4.z, b4.w };
#pragma unroll
            for (int i = 0; i < 4; ++i)
#pragma unroll
                for (int j = 0; j < 4; ++j) acc[i][j] += av[i] * bv[j];
        }
        __syncthreads();
    }
#pragma unroll
    for (int i = 0; i < 4; ++i) {
        int gm = m0 + tm + 16 * i;
        if (gm >= M) continue;
#pragma unroll
        for (int j = 0; j < 4; ++j) {
            int gn = n0 + tn * 4 + j;
            if (gn >= N) continue;
            float v = acc[i][j];
            if (EPI == 1) v += addp[(size_t)gm * ldadd + gn];
            C[(size_t)gm * ldc + gn] = v;
        }
    }
}

// ---------------- q build: split + RoPE ----------------
__global__ void k_build_q(const float* __restrict__ qcr, float* __restrict__ qb) {
    int gid = blockIdx.x * 256 + threadIdx.x;   // 16*2048*96
    int d = gid % 96;
    int rs = gid / 96;
    int srow = rs & 2047;
    int bh = rs >> 11;
    int b = bh >> 3, h = bh & 7;
    int t = b * 2048 + srow;
    const float* src = qcr + (size_t)t * 768 + h * 96;
    float val;
    if (d < 64) {
        val = src[d];
    } else {
        int d2 = d - 64;
        int fi = d2 & 15;
        float ang = (float)srow * __expf(-((float)(2 * fi) / 32.f) * 9.210340371976184f);
        float s, c; __sincosf(ang, &s, &c);
        float x = src[64 + d2];
        float r = (d2 < 16) ? -src[64 + d2 + 16] : src[64 + d2 - 16];
        val = x * c + r * s;
    }
    qb[gid] = val;
}

// ---------------- k/v build: split + RoPE(k_r broadcast) ----------------
__global__ void k_build_kv(const float* __restrict__ kv, const float* __restrict__ ckv,
                           float* __restrict__ kb, float* __restrict__ vb) {
    int gid = blockIdx.x * 256 + threadIdx.x;   // 16*2048*160
    int d = gid % 160;
    int rs = gid / 160;
    int srow = rs & 2047;
    int bh = rs >> 11;
    int b = bh >> 3, h = bh & 7;
    int t = b * 2048 + srow;
    if (d < 96) {
        float val;
        if (d < 64) {
            val = kv[(size_t)t * 1024 + h * 128 + d];
        } else {
            int d2 = d - 64;
            int fi = d2 & 15;
            float ang = (float)srow * __expf(-((float)(2 * fi) / 32.f) * 9.210340371976184f);
            float s, c; __sincosf(ang, &s, &c);
            float x = ckv[(size_t)t * 160 + 128 + d2];
            float r = (d2 < 16) ? -ckv[(size_t)t * 160 + 128 + d2 + 16]
                                :  ckv[(size_t)t * 160 + 128 + d2 - 16];
            val = x * c + r * s;
        }
        kb[((size_t)bh * 2048 + srow) * 96 + d] = val;
    } else {
        vb[((size_t)bh * 2048 + srow) * 64 + (d - 96)] = kv[(size_t)t * 1024 + h * 128 + 64 + (d - 96)];
    }
}

// ---------------- flash attention (f32), 1 wave = 64 q rows ----------------
__global__ __launch_bounds__(64)
void k_attn(const float* __restrict__ qb, const float* __restrict__ kb,
            const float* __restrict__ vb, float* __restrict__ ao) {
    int lane = threadIdx.x;
    int blk = blockIdx.x;          // 512 = 16 bh * 32 qtiles
    int bh = blk >> 5;
    int qt = blk & 31;
    int b = bh >> 3, h = bh & 7;
    int row = qt * 64 + lane;
    const float* qp = qb + ((size_t)bh * 2048 + row) * 96;
    float q[96];
#pragma unroll
    for (int d = 0; d < 96; ++d) q[d] = qp[d];
    float acc[64];
#pragma unroll
    for (int d = 0; d < 64; ++d) acc[d] = 0.f;
    float m = -INFINITY, l = 0.f;
    __shared__ float kl[16][96];
    __shared__ float vl[16][64];
    const float* kbase = kb + (size_t)bh * 2048 * 96;
    const float* vbase = vb + (size_t)bh * 2048 * 64;
    const float scale = 0.10206207261596575f;  // 1/sqrt(96)
    for (int k0 = 0; k0 < 2048; k0 += 16) {
        __syncthreads();
#pragma unroll
        for (int i = 0; i < 24; ++i) { int idx = i * 64 + lane; ((float*)kl)[idx] = kbase[(size_t)k0 * 96 + idx]; }
#pragma unroll
        for (int i = 0; i < 16; ++i) { int idx = i * 64 + lane; ((float*)vl)[idx] = vbase[(size_t)k0 * 64 + idx]; }
        __syncthreads();
        float sv[16];
#pragma unroll
        for (int j = 0; j < 16; ++j) {
            float s = 0.f;
#pragma unroll
            for (int d = 0; d < 96; ++d) s += q[d] * kl[j][d];
            sv[j] = s * scale;
        }
        float tmx = m;
#pragma unroll
        for (int j = 0; j < 16; ++j) tmx = fmaxf(tmx, sv[j]);
        float corr = __expf(m - tmx);
        m = tmx;
        l *= corr;
#pragma unroll
        for (int d = 0; d < 64; ++d) acc[d] *= corr;
#pragma unroll
        for (int j = 0; j < 16; ++j) {
            float p = __expf(sv[j] - m);
            l += p;
#pragma unroll
            for (int d = 0; d < 64; ++d) acc[d] += p * vl[j][d];
        }
    }
    int t = b * 2048 + row;
    float inv = 1.f / l;
    float* op = ao + (size_t)t * 512 + h * 64;
#pragma unroll
    for (int d = 0; d < 64; ++d) op[d] = acc[d] * inv;
}

// ---------------- swiglu elementwise: g <- silu(g)*u ----------------
__global__ void k_swiglu(float* __restrict__ g, const float* __restrict__ u, int n) {
    int i = blockIdx.x * 256 + threadIdx.x;
    if (i < n) { float gv = g[i]; g[i] = gv / (1.f + __expf(-gv)) * u[i]; }
}

// ---------------- router: sigmoid gate + top-4 + scatter to expert lists ----------------
__global__ __launch_bounds__(64)
void k_router(const float* __restrict__ xn2, const float* __restrict__ wg,
              float* __restrict__ ewt, int* __restrict__ ecnt, int* __restrict__ etok) {
    int t = blockIdx.x, tid = threadIdx.x;
    __shared__ float xs[512];
    __shared__ float sc[16];
    const float* xp = xn2 + (size_t)t * 512;
    for (int i = tid; i < 512; i += 64) xs[i] = xp[i];
    __syncthreads();
    if (tid < 16) {
        float s = 0.f;
        for (int k = 0; k < 512; ++k) s += xs[k] * wg[k * 16 + tid];
        sc[tid] = 1.f / (1.f + expf(-s));
    }
    __syncthreads();
    if (tid == 0) {
        float tw[4]; int ti[4]; unsigned used = 0;
#pragma unroll
        for (int kk = 0; kk < 4; ++kk) {
            float bv = -1e30f; int bi = 0;
            for (int e = 0; e < 16; ++e)
                if (!((used >> e) & 1) && sc[e] > bv) { bv = sc[e]; bi = e; }
            used |= 1u << bi; tw[kk] = bv; ti[kk] = bi;
        }
        float inv = 1.f / (tw[0] + tw[1] + tw[2] + tw[3]);
        for (int kk = 0; kk < 4; ++kk) {
            int e = ti[kk];
            int slot = atomicAdd(&ecnt[e], 1);
            etok[e * 4096 + slot] = t * 4 + kk;
            ewt[e * 4096 + slot] = tw[kk] * inv;
        }
    }
}

// ---------------- MoE stage 1: act = silu(x@wg)*(x@wu), gathered per expert ----------------
__global__ __launch_bounds__(256)
void k_moe1(const float* __restrict__ xn2, const float* __restrict__ rwg, const float* __restrict__ rwu,
            const int* __restrict__ ecnt, const int* __restrict__ etok, float* __restrict__ eact) {
    int e = blockIdx.x >> 6;
    int tt = blockIdx.x & 63;
    int n0 = blockIdx.y * 64;
    int cnt = ecnt[e];
    int base = tt * 64;
    if (base >= cnt) return;
    int rows = min(64, cnt - base);
    __shared__ int toks[64];
    __shared__ float As[64][17];
    __shared__ float Bg[16][64];
    __shared__ float Bu[16][64];
    int tid = threadIdx.x;
    if (tid < 64) toks[tid] = (base + tid < cnt) ? etok[e * 4096 + base + tid] : 0;
    __syncthreads();
    int tm = tid & 15, tn = tid >> 4;
    const float* wgp = rwg + (size_t)e * 512 * 256;
    const float* wup = rwu + (size_t)e * 512 * 256;
    float ag[4][4] = {}, au[4][4] = {};
    for (int k0 = 0; k0 < 512; k0 += 16) {
#pragma unroll
        for (int i = 0; i < 4; ++i) {
            int idx = i * 256 + tid;
            int mm = idx >> 4, k = idx & 15;
            As[mm][k] = (mm < rows) ? xn2[(size_t)(toks[mm] >> 2) * 512 + k0 + k] : 0.f;
        }
#pragma unroll
        for (int i = 0; i < 4; ++i) {
            int idx = i * 256 + tid;
            int k = idx >> 6, n = idx & 63;
            Bg[k][n] = wgp[(size_t)(k0 + k) * 256 + n0 + n];
            Bu[k][n] = wup[(size_t)(k0 + k) * 256 + n0 + n];
        }
        __syncthreads();
#pragma unroll
        for (int k = 0; k < 16; ++k) {
            float av[4] = { As[tm][k], As[tm + 16][k], As[tm + 32][k], As[tm + 48][k] };
            float4 bg4 = *(const float4*)&Bg[k][tn * 4];
            float4 bu4 = *(const float4*)&Bu[k][tn * 4];
            float bg[4] = { bg4.x, bg4.y, bg4.z, bg4.w };
            float bu[4] = { bu4.x, bu4.y, bu4.z, bu4.w };
#pragma unroll
            for (int i = 0; i < 4; ++i)
#pragma unroll
                for (int j = 0; j < 4; ++j) { ag[i][j] += av[i] * bg[j]; au[i][j] += av[i] * bu[j]; }
        }
        __syncthreads();
    }
#pragma unroll
    for (int i = 0; i < 4; ++i) {
        int r = tm + 16 * i;
        if (r >= rows) continue;
        int entry = toks[r];
#pragma unroll
        for (int j = 0; j < 4; ++j) {
            float gv = ag[i][j], uv = au[i][j];
            eact[(size_t)entry * 256 + n0 + tn * 4 + j] = gv / (1.f + __expf(-gv)) * uv;
        }
    }
}

// ---------------- MoE stage 2: y = act @ wd, weighted atomic accumulate ----------------
__global__ __launch_bounds__(256)
void k_moe2(const float* __restrict__ eact, const float* __restrict__ rwd,
            const int* __restrict__ ecnt, const int* __restrict__ etok,
            const float* __restrict__ ewt, float* __restrict__ oacc) {
    int e = blockIdx.x >> 6;
    int tt = blockIdx.x & 63;
    int n0 = blockIdx.y * 64;
    int cnt = ecnt[e];
    int base = tt * 64;
    if (base >= cnt) return;
    int rows = min(64, cnt - base);
    __shared__ int toks[64];
    __shared__ float wts[64];
    __shared__ float As[64][17];
    __shared__ float Bs[16][64];
    int tid = threadIdx.x;
    if (tid < 64) {
        toks[tid] = (base + tid < cnt) ? etok[e * 4096 + base + tid] : 0;
        wts[tid] = (base + tid < cnt) ? ewt[e * 4096 + base + tid] : 0.f;
    }
    __syncthreads();
    int tm = tid & 15, tn = tid >> 4;
    const float* wdp = rwd + (size_t)e * 256 * 512;
    float acc[4][4] = {};
    for (int k0 = 0; k0 < 256; k0 += 16) {
#pragma unroll
        for (int i = 0; i < 4; ++i) {
            int idx = i * 256 + tid;
            int mm = idx >> 4, k = idx & 15;
            As[mm][k] = (mm < rows) ? eact[(size_t)toks[mm] * 256 + k0 + k] : 0.f;
        }
#pragma unroll
        for (int i = 0; i < 4; ++i) {
            int idx = i * 256 + tid;
            int k = idx >> 6, n = idx & 63;
            Bs[k][n] = wdp[(size_t)(k0 + k) * 512 + n0 + n];
        }
        __syncthreads();
#pragma unroll
        for (int k = 0; k < 16; ++k) {
            float av[4] = { As[tm][k], As[tm + 16][k], As[tm + 32][k], As[tm + 48][k] };
            float4 b4 = *(const float4*)&Bs[k][tn * 4];
            float bv[4] = { b4.x, b4.y, b4.z, b4.w };
#pragma unroll
            for (int i = 0; i < 4; ++i)
#pragma unroll
                for (int j = 0; j < 4; ++j) acc[i][j] += av[i] * bv[j];
        }
        __syncthreads();
    }
#pragma unroll
    for (int i = 0; i < 4; ++i) {
        int r = tm + 16 * i;
        if (r >= rows) continue;
        int tkn = toks[r] >> 2;
        float w = wts[r];
#pragma unroll
        for (int j = 0; j < 4; ++j)
            atomicAdd(&oacc[(size_t)tkn * 512 + n0 + tn * 4 + j], acc[i][j] * w);
    }
}

// ---------------- finalize: copy f32 accumulator to output ----------------
__global__ void k_final(const float* __restrict__ oacc, float* __restrict__ out, int n) {
    int i = blockIdx.x * 256 + threadIdx.x;
    if (i < n) out[i] = oacc[i];
}

// ---------------- host launcher ----------------
extern "C" void kernel_launch(void* const* d_in, const int* in_sizes, int n_in,
                              void* d_out, int out_size, void* d_ws, size_t ws_size,
                              hipStream_t stream) {
    const float* hs       = (const float*)d_in[0];
    const float* w_innorm = (const float*)d_in[1];
    const float* w_dq     = (const float*)d_in[2];
    const float* w_qnorm  = (const float*)d_in[3];
    const float* w_uq     = (const float*)d_in[4];
    const float* w_dkv    = (const float*)d_in[5];
    const float* w_kvnorm = (const float*)d_in[6];
    const float* w_ukv    = (const float*)d_in[7];
    const float* w_o      = (const float*)d_in[8];
    const float* w_post   = (const float*)d_in[9];
    const float* w_gate   = (const float*)d_in[10];
    const float* sh_wg    = (const float*)d_in[11];
    const float* sh_wu    = (const float*)d_in[12];
    const float* sh_wd    = (const float*)d_in[13];
    const float* r_wg     = (const float*)d_in[14];
    const float* r_wu     = (const float*)d_in[15];
    const float* r_wd     = (const float*)d_in[16];

    float* ws   = (float*)d_ws;
    float* xn   = ws + OFF_XN;
    float* cq   = ws + OFF_CQ;
    float* ckv  = ws + OFF_CKV;
    float* cqn  = ws + OFF_CQN;
    float* ckvn = ws + OFF_CKVN;
    float* qcr  = ws + OFF_QCR;
    float* kvb  = ws + OFF_KV;
    float* qb   = ws + OFF_QB;
    float* kb   = ws + OFF_KB;
    float* vb   = ws + OFF_VB;
    float* ao   = ws + OFF_AO;
    float* r2   = ws + OFF_R2;
    float* xn2  = ws + OFF_XN2;
    float* g    = ws + OFF_G;
    float* u    = ws + OFF_U;
    float* oacc = ws + OFF_OACC;
    float* ewt  = ws + OFF_EWT;
    float* eact = ws + OFF_EACT;
    int*   ecnt = (int*)(ws + OFF_ECNT);
    int*   etok = (int*)(ws + OFF_ETOK);

    // 1. input RMSNorm
    k_rms<<<Tt, 256, 0, stream>>>(hs, 512, w_innorm, xn, 512, 512);
    // 2. down-projections
    k_gemm<0><<<dim3(4, 64), 256, 0, stream>>>(xn, 512, w_dq, 256, cq, 256, Tt, 256, 512, nullptr, 0);
    k_gemm<0><<<dim3(3, 64), 256, 0, stream>>>(xn, 512, w_dkv, 160, ckv, 160, Tt, 160, 512, nullptr, 0);
    // 3. latent norms
    k_rms<<<Tt, 256, 0, stream>>>(cq, 256, w_qnorm, cqn, 256, 256);
    k_rms<<<Tt, 256, 0, stream>>>(ckv, 160, w_kvnorm, ckvn, 128, 128);
    // 4. up-projections
    k_gemm<0><<<dim3(12, 64), 256, 0, stream>>>(cqn, 256, w_uq, 768, qcr, 768, Tt, 768, 256, nullptr, 0);
    k_gemm<0><<<dim3(16, 64), 256, 0, stream>>>(ckvn, 128, w_ukv, 1024, kvb, 1024, Tt, 1024, 128, nullptr, 0);
    // 5. build q/k/v with RoPE
    k_build_q<<<(16 * 2048 * 96) / 256, 256, 0, stream>>>(qcr, qb);
    k_build_kv<<<(16 * 2048 * 160) / 256, 256, 0, stream>>>(kvb, ckv, kb, vb);
    // 6. attention
    k_attn<<<512, 64, 0, stream>>>(qb, kb, vb, ao);
    // 7. output proj + residual
    k_gemm<1><<<dim3(8, 64), 256, 0, stream>>>(ao, 512, w_o, 512, r2, 512, Tt, 512, 512, hs, 512);
    // 8. post norm
    k_rms<<<Tt, 256, 0, stream>>>(r2, 512, w_post, xn2, 512, 512);
    // 9. shared expert
    k_gemm<0><<<dim3(4, 64), 256, 0, stream>>>(xn2, 512, sh_wg, 256, g, 256, Tt, 256, 512, nullptr, 0);
    k_gemm<0><<<dim3(4, 64), 256, 0, stream>>>(xn2, 512, sh_wu, 256, u, 256, Tt, 256, 512, nullptr, 0);
    k_swiglu<<<(Tt * 256) / 256, 256, 0, stream>>>(g, u, Tt * 256);
    k_gemm<1><<<dim3(8, 64), 256, 0, stream>>>(g, 256, sh_wd, 512, oacc, 512, Tt, 512, 256, r2, 512);
    // 10. router + MoE
    hipMemsetAsync(ecnt, 0, NEn * sizeof(int), stream);
    k_router<<<Tt, 64, 0, stream>>>(xn2, w_gate, ewt, ecnt, etok);
    k_moe1<<<dim3(1024, 4), 256, 0, stream>>>(xn2, r_wg, r_wu, ecnt, etok, eact);
    k_moe2<<<dim3(1024, 8), 256, 0, stream>>>(eact, r_wd, ecnt, etok, ewt, oacc);
    // 11. finalize
    k_final<<<(Tt * 512) / 256, 256, 0, stream>>>(oacc, (float*)d_out, Tt * 512);
}

// Round 3
// 570.336 us; speedup vs baseline: 7.2893x; 7.2893x over previous
//
#include <hip/hip_runtime.h>
#include <hip/hip_bf16.h>
#include <math.h>

typedef float f32x4 __attribute__((ext_vector_type(4)));
typedef short s16x8 __attribute__((ext_vector_type(8)));

// ---------------- problem constants ----------------
constexpr int Tt = 4096;
constexpr int HID = 512, NEn = 16;
constexpr float EPSf = 1.1920929e-07f;

__device__ __forceinline__ short f2b(float f) {
    union { __hip_bfloat16 h; short s; } u;
    u.h = __float2bfloat16(f);
    return u.s;
}

// ---------------- workspace layout (float elements, 16-float aligned) ----------------
constexpr size_t alg(size_t x) { return (x + 15) & ~(size_t)15; }
// f32 buffers
constexpr size_t OFF_CQ   = 0;                                   // T*256 f32
constexpr size_t OFF_CKV  = alg(OFF_CQ   + (size_t)Tt * 256);    // T*160 f32
constexpr size_t OFF_QCR  = alg(OFF_CKV  + (size_t)Tt * 160);    // T*768 f32
constexpr size_t OFF_KVB  = alg(OFF_QCR  + (size_t)Tt * 768);    // T*1024 f32
constexpr size_t OFF_R2   = alg(OFF_KVB  + (size_t)Tt * 1024);   // T*512 f32
constexpr size_t OFF_XN2  = alg(OFF_R2   + (size_t)Tt * 512);    // T*512 f32
constexpr size_t OFF_G    = alg(OFF_XN2  + (size_t)Tt * 512);    // T*256 f32
constexpr size_t OFF_U    = alg(OFF_G    + (size_t)Tt * 256);    // T*256 f32
constexpr size_t OFF_OACC = alg(OFF_U    + (size_t)Tt * 256);    // T*512 f32
constexpr size_t OFF_EWT  = alg(OFF_OACC + (size_t)Tt * 512);    // 16*4096 f32
constexpr size_t OFF_ECNT = alg(OFF_EWT  + (size_t)NEn * Tt);    // ints
constexpr size_t OFF_ETOK = alg(OFF_ECNT + 64);                  // 16*4096 ints
// bf16 buffers (element counts halved into float units)
constexpr size_t OFF_XNB   = alg(OFF_ETOK + (size_t)NEn * Tt);       // T*512 bf16
constexpr size_t OFF_CQNB  = alg(OFF_XNB   + (size_t)Tt * 512 / 2);  // T*256 bf16
constexpr size_t OFF_CKVNB = alg(OFF_CQNB  + (size_t)Tt * 256 / 2);  // T*128 bf16
constexpr size_t OFF_QB    = alg(OFF_CKVNB + (size_t)Tt * 128 / 2);  // 16*2048*96 bf16
constexpr size_t OFF_KB    = alg(OFF_QB    + (size_t)16 * 2048 * 96 / 2);
constexpr size_t OFF_VBT   = alg(OFF_KB    + (size_t)16 * 2048 * 96 / 2); // 16*64*2048 bf16
constexpr size_t OFF_AOB   = alg(OFF_VBT   + (size_t)16 * 64 * 2048 / 2); // T*512 bf16
constexpr size_t OFF_XN2B  = alg(OFF_AOB   + (size_t)Tt * 512 / 2);
constexpr size_t OFF_GACT  = alg(OFF_XN2B  + (size_t)Tt * 512 / 2);  // T*256 bf16
constexpr size_t OFF_EACT  = alg(OFF_GACT  + (size_t)Tt * 256 / 2);  // 16384*256 bf16
// transposed bf16 weights [N][K]
constexpr size_t OFF_WDQT  = alg(OFF_EACT  + (size_t)16384 * 256 / 2);
constexpr size_t OFF_WDKVT = alg(OFF_WDQT  + (size_t)256 * 512 / 2);
constexpr size_t OFF_WUQT  = alg(OFF_WDKVT + (size_t)160 * 512 / 2);
constexpr size_t OFF_WUKVT = alg(OFF_WUQT  + (size_t)768 * 256 / 2);
constexpr size_t OFF_WOT   = alg(OFF_WUKVT + (size_t)1024 * 128 / 2);
constexpr size_t OFF_SHWGT = alg(OFF_WOT   + (size_t)512 * 512 / 2);
constexpr size_t OFF_SHWUT = alg(OFF_SHWGT + (size_t)256 * 512 / 2);
constexpr size_t OFF_SHWDT = alg(OFF_SHWUT + (size_t)256 * 512 / 2);
constexpr size_t OFF_RWGT  = alg(OFF_SHWDT + (size_t)512 * 256 / 2);
constexpr size_t OFF_RWUT  = alg(OFF_RWGT  + (size_t)16 * 256 * 512 / 2);
constexpr size_t OFF_RWDT  = alg(OFF_RWUT  + (size_t)16 * 256 * 512 / 2);
constexpr size_t OFF_END   = alg(OFF_RWDT  + (size_t)16 * 512 * 256 / 2);

// ---------------- convert + transpose: src f32 [E][K][N] -> dst bf16 [E][N][K] ----------------
__global__ void k_cvt_t(const float* __restrict__ src, short* __restrict__ dst, int K, int N) {
    __shared__ float t[32][33];
    int n0 = blockIdx.x * 32, k0 = blockIdx.y * 32;
    size_t eo = (size_t)blockIdx.z * K * N;
    int c = threadIdx.x & 31, r = threadIdx.x >> 5;
#pragma unroll
    for (int i = 0; i < 4; ++i)
        t[r + 8 * i][c] = src[eo + (size_t)(k0 + r + 8 * i) * N + n0 + c];
    __syncthreads();
#pragma unroll
    for (int i = 0; i < 4; ++i)
        dst[eo + (size_t)(n0 + r + 8 * i) * K + k0 + c] = f2b(t[c][r + 8 * i]);
}

// ---------------- RMSNorm f32 in -> bf16 out (+ optional f32 out) ----------------
__global__ void k_rms(const float* __restrict__ in, int inStride, const float* __restrict__ w,
                      float* __restrict__ outF, short* __restrict__ outB, int outStride, int D) {
    int row = blockIdx.x, tid = threadIdx.x;
    __shared__ float xs[512];
    __shared__ float red[256];
    const float* ip = in + (size_t)row * inStride;
    float ss = 0.f;
    for (int i = tid; i < D; i += 256) { float v = ip[i]; xs[i] = v; ss += v * v; }
    red[tid] = ss; __syncthreads();
    for (int s = 128; s > 0; s >>= 1) { if (tid < s) red[tid] += red[tid + s]; __syncthreads(); }
    float sc = rsqrtf(red[0] / (float)D + EPSf);
    for (int i = tid; i < D; i += 256) {
        float v = xs[i] * sc * w[i];
        outB[(size_t)row * outStride + i] = f2b(v);
        if (outF) outF[(size_t)row * outStride + i] = v;
    }
}

// ---------------- MFMA GEMM: C(f32)[4096][N] = A_b(bf16)[4096][K] @ B (BT bf16 [N][K]) ----------------
template <int EPI>  // 0: plain, 1: + f32 residual
__global__ __launch_bounds__(256)
void k_mgemm(const short* __restrict__ A, const short* __restrict__ BT,
             float* __restrict__ C, const float* __restrict__ add, int N, int K) {
    __shared__ __align__(16) short As[128 * 64];
    __shared__ __align__(16) short Bs[64 * 64];
    int tid = threadIdx.x;
    int w = tid >> 6, l = tid & 63, g = l >> 4, li = l & 15;
    int wm = w >> 1, wn = w & 1;
    int m0 = blockIdx.y * 128, n0 = blockIdx.x * 64;
    f32x4 acc[4][2] = {};
    for (int k0 = 0; k0 < K; k0 += 64) {
        __syncthreads();
#pragma unroll
        for (int p = 0; p < 4; ++p) {
            int flat = p * 256 + tid;
            int row = flat >> 3, ch = flat & 7;
            *(int4*)&As[row * 64 + ((ch ^ (row & 7)) * 8)] =
                *(const int4*)(A + (size_t)(m0 + row) * K + k0 + 8 * ch);
        }
#pragma unroll
        for (int p = 0; p < 2; ++p) {
            int flat = p * 256 + tid;
            int n = flat >> 3, ch = flat & 7;
            int4 v = {0, 0, 0, 0};
            if (n0 + n < N) v = *(const int4*)(BT + (size_t)(n0 + n) * K + k0 + 8 * ch);
            *(int4*)&Bs[n * 64 + ((ch ^ (n & 7)) * 8)] = v;
        }
        __syncthreads();
#pragma unroll
        for (int kc = 0; kc < 2; ++kc) {
            s16x8 af[4], bf[2];
#pragma unroll
            for (int mt = 0; mt < 4; ++mt) {
                int row = wm * 64 + mt * 16 + li;
                af[mt] = *(const s16x8*)&As[row * 64 + (((4 * kc + g) ^ (li & 7)) * 8)];
            }
#pragma unroll
            for (int nt = 0; nt < 2; ++nt) {
                int n = wn * 32 + nt * 16 + li;
                bf[nt] = *(const s16x8*)&Bs[n * 64 + (((4 * kc + g) ^ (li & 7)) * 8)];
            }
#pragma unroll
            for (int mt = 0; mt < 4; ++mt)
#pragma unroll
                for (int nt = 0; nt < 2; ++nt)
                    acc[mt][nt] = __builtin_amdgcn_mfma_f32_16x16x32_bf16(af[mt], bf[nt], acc[mt][nt], 0, 0, 0);
        }
    }
#pragma unroll
    for (int mt = 0; mt < 4; ++mt)
#pragma unroll
        for (int nt = 0; nt < 2; ++nt)
#pragma unroll
            for (int r = 0; r < 4; ++r) {
                int gm = m0 + wm * 64 + mt * 16 + 4 * g + r;
                int gn = n0 + wn * 32 + nt * 16 + li;
                if (gn < N) {
                    float v = acc[mt][nt][r];
                    if (EPI == 1) v += add[(size_t)gm * N + gn];
                    C[(size_t)gm * N + gn] = v;
                }
            }
}

// ---------------- q build: split + RoPE -> bf16 ----------------
__global__ void k_build_q(const float* __restrict__ qcr, short* __restrict__ qb) {
    int gid = blockIdx.x * 256 + threadIdx.x;   // 16*2048*96
    int d = gid % 96;
    int rs = gid / 96;
    int srow = rs & 2047;
    int bh = rs >> 11;
    int b = bh >> 3, h = bh & 7;
    int t = b * 2048 + srow;
    const float* src = qcr + (size_t)t * 768 + h * 96;
    float val;
    if (d < 64) {
        val = src[d];
    } else {
        int d2 = d - 64;
        int fi = d2 & 15;
        float ang = (float)srow * __expf(-((float)(2 * fi) / 32.f) * 9.210340371976184f);
        float s, c; __sincosf(ang, &s, &c);
        float x = src[64 + d2];
        float r = (d2 < 16) ? -src[64 + d2 + 16] : src[64 + d2 - 16];
        val = x * c + r * s;
    }
    qb[gid] = f2b(val);
}

// ---------------- k build: split + RoPE(k_r broadcast) -> bf16 ----------------
__global__ void k_build_k(const float* __restrict__ kvb, const float* __restrict__ ckv,
                          short* __restrict__ kb) {
    int gid = blockIdx.x * 256 + threadIdx.x;   // 16*2048*96
    int d = gid % 96;
    int rs = gid / 96;
    int srow = rs & 2047;
    int bh = rs >> 11;
    int b = bh >> 3, h = bh & 7;
    int t = b * 2048 + srow;
    float val;
    if (d < 64) {
        val = kvb[(size_t)t * 1024 + h * 128 + d];
    } else {
        int d2 = d - 64;
        int fi = d2 & 15;
        float ang = (float)srow * __expf(-((float)(2 * fi) / 32.f) * 9.210340371976184f);
        float s, c; __sincosf(ang, &s, &c);
        float x = ckv[(size_t)t * 160 + 128 + d2];
        float r = (d2 < 16) ? -ckv[(size_t)t * 160 + 128 + d2 + 16]
                            :  ckv[(size_t)t * 160 + 128 + d2 - 16];
        val = x * c + r * s;
    }
    kb[gid] = f2b(val);
}

// ---------------- v build transposed: vbt[bh][dim64][key2048] bf16 ----------------
__global__ void k_build_vt(const float* __restrict__ kvb, short* __restrict__ vbt) {
    int gid = blockIdx.x * 256 + threadIdx.x;   // 16*64*2048
    int key = gid & 2047;
    int dim = (gid >> 11) & 63;
    int bh = gid >> 17;
    int b = bh >> 3, h = bh & 7;
    vbt[gid] = f2b(kvb[(size_t)(b * 2048 + key) * 1024 + h * 128 + 64 + dim]);
}

// ---------------- MFMA flash attention: 4 waves/block, wave = 16 q cols ----------------
__global__ __launch_bounds__(256)
void k_attn(const short* __restrict__ qb, const short* __restrict__ kb,
            const short* __restrict__ vbt, short* __restrict__ ao) {
    __shared__ __align__(16) short Ks[64 * 96];
    __shared__ __align__(16) short Vs[64 * 64];
    int tid = threadIdx.x;
    int w = tid >> 6, l = tid & 63, g = l >> 4, li = l & 15;
    int bh = blockIdx.x >> 5, qt = blockIdx.x & 31;
    int b = bh >> 3, h = bh & 7;
    int qcol = qt * 64 + w * 16 + li;
    const float scale = 0.10206207261596575f;  // 1/sqrt(96)

    s16x8 qf[3];
    const short* qp = qb + (size_t)(bh * 2048 + qcol) * 96;
#pragma unroll
    for (int c = 0; c < 3; ++c) qf[c] = *(const s16x8*)(qp + 32 * c + 8 * g);

    f32x4 o[4] = {};
    float m = -INFINITY, lsum = 0.f;
    const short* kbase = kb + (size_t)bh * 2048 * 96;
    const short* vbase = vbt + (size_t)bh * 64 * 2048;

    for (int k0 = 0; k0 < 2048; k0 += 64) {
        __syncthreads();
#pragma unroll
        for (int p = 0; p < 3; ++p) {
            int flat = p * 256 + tid;
            int key = flat / 12, u = flat % 12;
            *(int4*)&Ks[key * 96 + 8 * u] = *(const int4*)(kbase + (size_t)(k0 + key) * 96 + 8 * u);
        }
#pragma unroll
        for (int p = 0; p < 2; ++p) {
            int flat = p * 256 + tid;
            int dim = flat >> 3, kc8 = flat & 7;
            int4 v = *(const int4*)(vbase + (size_t)dim * 2048 + k0 + 8 * kc8);
            int sw = dim & 15;
            *(int2*)&Vs[dim * 64 + (((2 * kc8) ^ sw) * 4)]     = make_int2(v.x, v.y);
            *(int2*)&Vs[dim * 64 + (((2 * kc8 + 1) ^ sw) * 4)] = make_int2(v.z, v.w);
        }
        __syncthreads();

        // S^T[key][q] = K · Q^T
        f32x4 s[4];
#pragma unroll
        for (int kt = 0; kt < 4; ++kt) {
            f32x4 acc = {};
#pragma unroll
            for (int c = 0; c < 3; ++c) {
                s16x8 kf = *(const s16x8*)&Ks[(kt * 16 + li) * 96 + 32 * c + 8 * g];
                acc = __builtin_amdgcn_mfma_f32_16x16x32_bf16(kf, qf[c], acc, 0, 0, 0);
            }
#pragma unroll
            for (int r = 0; r < 4; ++r) acc[r] *= scale;
            s[kt] = acc;
        }
        // per-q max over 64 keys
        float pm = -INFINITY;
#pragma unroll
        for (int kt = 0; kt < 4; ++kt)
#pragma unroll
            for (int r = 0; r < 4; ++r) pm = fmaxf(pm, s[kt][r]);
        pm = fmaxf(pm, __shfl_xor(pm, 16));
        pm = fmaxf(pm, __shfl_xor(pm, 32));
        float mn = fmaxf(m, pm);
        float corr = __expf(m - mn);
        float ps = 0.f;
#pragma unroll
        for (int kt = 0; kt < 4; ++kt)
#pragma unroll
            for (int r = 0; r < 4; ++r) { float p = __expf(s[kt][r] - mn); s[kt][r] = p; ps += p; }
        ps += __shfl_xor(ps, 16);
        ps += __shfl_xor(ps, 32);
        lsum = lsum * corr + ps;
        m = mn;
#pragma unroll
        for (int dt = 0; dt < 4; ++dt)
#pragma unroll
            for (int r = 0; r < 4; ++r) o[dt][r] *= corr;

        // P^T fragments (lane-local)
        s16x8 pf[2];
#pragma unroll
        for (int kc = 0; kc < 2; ++kc) {
            s16x8 t;
#pragma unroll
            for (int r = 0; r < 4; ++r) { t[r] = f2b(s[2 * kc][r]); t[4 + r] = f2b(s[2 * kc + 1][r]); }
            pf[kc] = t;
        }
        // O^T += V^T · P^T
#pragma unroll
        for (int dt = 0; dt < 4; ++dt) {
            int dim = dt * 16 + li;
#pragma unroll
            for (int kc = 0; kc < 2; ++kc) {
                int2 a0 = *(const int2*)&Vs[dim * 64 + (((8 * kc + g) ^ li) * 4)];
                int2 a1 = *(const int2*)&Vs[dim * 64 + (((8 * kc + 4 + g) ^ li) * 4)];
                union { s16x8 v; int i[4]; } vf;
                vf.i[0] = a0.x; vf.i[1] = a0.y; vf.i[2] = a1.x; vf.i[3] = a1.y;
                o[dt] = __builtin_amdgcn_mfma_f32_16x16x32_bf16(vf.v, pf[kc], o[dt], 0, 0, 0);
            }
        }
    }
    float inv = 1.f / lsum;
    short* op = ao + (size_t)(b * 2048 + qcol) * 512 + h * 64;
#pragma unroll
    for (int dt = 0; dt < 4; ++dt)
#pragma unroll
        for (int r = 0; r < 4; ++r)
            op[dt * 16 + 4 * g + r] = f2b(o[dt][r] * inv);
}

// ---------------- swiglu: gact(bf16) = silu(g)*u ----------------
__global__ void k_swiglu(const float* __restrict__ g, const float* __restrict__ u,
                         short* __restrict__ out, int n) {
    int i = blockIdx.x * 256 + threadIdx.x;
    if (i < n) { float gv = g[i]; out[i] = f2b(gv / (1.f + __expf(-gv)) * u[i]); }
}

// ---------------- router (exact f32) ----------------
__global__ __launch_bounds__(64)
void k_router(const float* __restrict__ xn2, const float* __restrict__ wg,
              float* __restrict__ ewt, int* __restrict__ ecnt, int* __restrict__ etok) {
    int t = blockIdx.x, tid = threadIdx.x;
    __shared__ float xs[512];
    __shared__ float sc[16];
    const float* xp = xn2 + (size_t)t * 512;
    for (int i = tid; i < 512; i += 64) xs[i] = xp[i];
    __syncthreads();
    if (tid < 16) {
        float s = 0.f;
        for (int k = 0; k < 512; ++k) s += xs[k] * wg[k * 16 + tid];
        sc[tid] = 1.f / (1.f + expf(-s));
    }
    __syncthreads();
    if (tid == 0) {
        float tw[4]; int ti[4]; unsigned used = 0;
#pragma unroll
        for (int kk = 0; kk < 4; ++kk) {
            float bv = -1e30f; int bi = 0;
            for (int e = 0; e < 16; ++e)
                if (!((used >> e) & 1) && sc[e] > bv) { bv = sc[e]; bi = e; }
            used |= 1u << bi; tw[kk] = bv; ti[kk] = bi;
        }
        float inv = 1.f / (tw[0] + tw[1] + tw[2] + tw[3]);
        for (int kk = 0; kk < 4; ++kk) {
            int e = ti[kk];
            int slot = atomicAdd(&ecnt[e], 1);
            etok[e * 4096 + slot] = t * 4 + kk;
            ewt[e * 4096 + slot] = tw[kk] * inv;
        }
    }
}

// ---------------- MoE stage 1 (MFMA): eact = silu(x@wg)*(x@wu) ----------------
__global__ __launch_bounds__(256)
void k_moe1m(const short* __restrict__ X, const short* __restrict__ WGt, const short* __restrict__ WUt,
             const int* __restrict__ ecnt, const int* __restrict__ etok, short* __restrict__ eact) {
    int e = blockIdx.x >> 5, mt128 = blockIdx.x & 31;
    int cnt = ecnt[e];
    int base = mt128 * 128;
    if (base >= cnt) return;
    int rows = min(128, cnt - base);
    int n0 = blockIdx.y * 64;
    __shared__ __align__(16) short As[128 * 64];
    __shared__ __align__(16) short Bg[64 * 64];
    __shared__ __align__(16) short Bu[64 * 64];
    __shared__ int toks[128];
    int tid = threadIdx.x;
    if (tid < 128) toks[tid] = (tid < rows) ? etok[e * 4096 + base + tid] : -1;
    __syncthreads();
    int w = tid >> 6, l = tid & 63, g = l >> 4, li = l & 15;
    int wm = w >> 1, wn = w & 1;
    const short* wgp = WGt + (size_t)e * 256 * 512;
    const short* wup = WUt + (size_t)e * 256 * 512;
    f32x4 ag[4][2] = {}, au[4][2] = {};
    for (int k0 = 0; k0 < 512; k0 += 64) {
        __syncthreads();
#pragma unroll
        for (int p = 0; p < 4; ++p) {
            int flat = p * 256 + tid;
            int row = flat >> 3, ch = flat & 7;
            int tk = toks[row];
            int4 v = {0, 0, 0, 0};
            if (tk >= 0) v = *(const int4*)(X + (size_t)(tk >> 2) * 512 + k0 + 8 * ch);
            *(int4*)&As[row * 64 + ((ch ^ (row & 7)) * 8)] = v;
        }
#pragma unroll
        for (int p = 0; p < 2; ++p) {
            int flat = p * 256 + tid;
            int n = flat >> 3, ch = flat & 7;
            *(int4*)&Bg[n * 64 + ((ch ^ (n & 7)) * 8)] = *(const int4*)(wgp + (size_t)(n0 + n) * 512 + k0 + 8 * ch);
            *(int4*)&Bu[n * 64 + ((ch ^ (n & 7)) * 8)] = *(const int4*)(wup + (size_t)(n0 + n) * 512 + k0 + 8 * ch);
        }
        __syncthreads();
#pragma unroll
        for (int kc = 0; kc < 2; ++kc) {
            s16x8 af[4], bg[2], bu[2];
#pragma unroll
            for (int mt = 0; mt < 4; ++mt) {
                int row = wm * 64 + mt * 16 + li;
                af[mt] = *(const s16x8*)&As[row * 64 + (((4 * kc + g) ^ (li & 7)) * 8)];
            }
#pragma unroll
            for (int nt = 0; nt < 2; ++nt) {
                int n = wn * 32 + nt * 16 + li;
                bg[nt] = *(const s16x8*)&Bg[n * 64 + (((4 * kc + g) ^ (li & 7)) * 8)];
                bu[nt] = *(const s16x8*)&Bu[n * 64 + (((4 * kc + g) ^ (li & 7)) * 8)];
            }
#pragma unroll
            for (int mt = 0; mt < 4; ++mt)
#pragma unroll
                for (int nt = 0; nt < 2; ++nt) {
                    ag[mt][nt] = __builtin_amdgcn_mfma_f32_16x16x32_bf16(af[mt], bg[nt], ag[mt][nt], 0, 0, 0);
                    au[mt][nt] = __builtin_amdgcn_mfma_f32_16x16x32_bf16(af[mt], bu[nt], au[mt][nt], 0, 0, 0);
                }
        }
    }
#pragma unroll
    for (int mt = 0; mt < 4; ++mt)
#pragma unroll
        for (int nt = 0; nt < 2; ++nt)
#pragma unroll
            for (int r = 0; r < 4; ++r) {
                int local = wm * 64 + mt * 16 + 4 * g + r;
                if (local < rows) {
                    int entry = toks[local];
                    int gn = n0 + wn * 32 + nt * 16 + li;
                    float gv = ag[mt][nt][r], uv = au[mt][nt][r];
                    eact[(size_t)entry * 256 + gn] = f2b(gv / (1.f + __expf(-gv)) * uv);
                }
            }
}

// ---------------- MoE stage 2 (MFMA): oacc += w * (eact @ wd) ----------------
__global__ __launch_bounds__(256)
void k_moe2m(const short* __restrict__ EA, const short* __restrict__ WDt,
             const int* __restrict__ ecnt, const int* __restrict__ etok,
             const float* __restrict__ ewt, float* __restrict__ oacc) {
    int e = blockIdx.x >> 5, mt128 = blockIdx.x & 31;
    int cnt = ecnt[e];
    int base = mt128 * 128;
    if (base >= cnt) return;
    int rows = min(128, cnt - base);
    int n0 = blockIdx.y * 64;
    __shared__ __align__(16) short As[128 * 64];
    __shared__ __align__(16) short Bs[64 * 64];
    __shared__ int toks[128];
    __shared__ float wts[128];
    int tid = threadIdx.x;
    if (tid < 128) {
        toks[tid] = (tid < rows) ? etok[e * 4096 + base + tid] : -1;
        wts[tid]  = (tid < rows) ? ewt[e * 4096 + base + tid] : 0.f;
    }
    __syncthreads();
    int w = tid >> 6, l = tid & 63, g = l >> 4, li = l & 15;
    int wm = w >> 1, wn = w & 1;
    const short* wdp = WDt + (size_t)e * 512 * 256;
    f32x4 acc[4][2] = {};
    for (int k0 = 0; k0 < 256; k0 += 64) {
        __syncthreads();
#pragma unroll
        for (int p = 0; p < 4; ++p) {
            int flat = p * 256 + tid;
            int row = flat >> 3, ch = flat & 7;
            int tk = toks[row];
            int4 v = {0, 0, 0, 0};
            if (tk >= 0) v = *(const int4*)(EA + (size_t)tk * 256 + k0 + 8 * ch);
            *(int4*)&As[row * 64 + ((ch ^ (row & 7)) * 8)] = v;
        }
#pragma unroll
        for (int p = 0; p < 2; ++p) {
            int flat = p * 256 + tid;
            int n = flat >> 3, ch = flat & 7;
            *(int4*)&Bs[n * 64 + ((ch ^ (n & 7)) * 8)] = *(const int4*)(wdp + (size_t)(n0 + n) * 256 + k0 + 8 * ch);
        }
        __syncthreads();
#pragma unroll
        for (int kc = 0; kc < 2; ++kc) {
            s16x8 af[4], bf[2];
#pragma unroll
            for (int mt = 0; mt < 4; ++mt) {
                int row = wm * 64 + mt * 16 + li;
                af[mt] = *(const s16x8*)&As[row * 64 + (((4 * kc + g) ^ (li & 7)) * 8)];
            }
#pragma unroll
            for (int nt = 0; nt < 2; ++nt) {
                int n = wn * 32 + nt * 16 + li;
                bf[nt] = *(const s16x8*)&Bs[n * 64 + (((4 * kc + g) ^ (li & 7)) * 8)];
            }
#pragma unroll
            for (int mt = 0; mt < 4; ++mt)
#pragma unroll
                for (int nt = 0; nt < 2; ++nt)
                    acc[mt][nt] = __builtin_amdgcn_mfma_f32_16x16x32_bf16(af[mt], bf[nt], acc[mt][nt], 0, 0, 0);
        }
    }
#pragma unroll
    for (int mt = 0; mt < 4; ++mt)
#pragma unroll
        for (int nt = 0; nt < 2; ++nt)
#pragma unroll
            for (int r = 0; r < 4; ++r) {
                int local = wm * 64 + mt * 16 + 4 * g + r;
                if (local < rows) {
                    int tok = toks[local] >> 2;
                    int gn = n0 + wn * 32 + nt * 16 + li;
                    atomicAdd(&oacc[(size_t)tok * 512 + gn], acc[mt][nt][r] * wts[local]);
                }
            }
}

// ---------------- finalize ----------------
__global__ void k_final(const float* __restrict__ oacc, float* __restrict__ out, int n) {
    int i = blockIdx.x * 256 + threadIdx.x;
    if (i < n) out[i] = oacc[i];
}

// ---------------- host launcher ----------------
extern "C" void kernel_launch(void* const* d_in, const int* in_sizes, int n_in,
                              void* d_out, int out_size, void* d_ws, size_t ws_size,
                              hipStream_t stream) {
    const float* hs       = (const float*)d_in[0];
    const float* w_innorm = (const float*)d_in[1];
    const float* w_dq     = (const float*)d_in[2];
    const float* w_qnorm  = (const float*)d_in[3];
    const float* w_uq     = (const float*)d_in[4];
    const float* w_dkv    = (const float*)d_in[5];
    const float* w_kvnorm = (const float*)d_in[6];
    const float* w_ukv    = (const float*)d_in[7];
    const float* w_o      = (const float*)d_in[8];
    const float* w_post   = (const float*)d_in[9];
    const float* w_gate   = (const float*)d_in[10];
    const float* sh_wg    = (const float*)d_in[11];
    const float* sh_wu    = (const float*)d_in[12];
    const float* sh_wd    = (const float*)d_in[13];
    const float* r_wg     = (const float*)d_in[14];
    const float* r_wu     = (const float*)d_in[15];
    const float* r_wd     = (const float*)d_in[16];

    float* ws   = (float*)d_ws;
    float* cq   = ws + OFF_CQ;
    float* ckv  = ws + OFF_CKV;
    float* qcr  = ws + OFF_QCR;
    float* kvb  = ws + OFF_KVB;
    float* r2   = ws + OFF_R2;
    float* xn2  = ws + OFF_XN2;
    float* g    = ws + OFF_G;
    float* u    = ws + OFF_U;
    float* oacc = ws + OFF_OACC;
    float* ewt  = ws + OFF_EWT;
    int*   ecnt = (int*)(ws + OFF_ECNT);
    int*   etok = (int*)(ws + OFF_ETOK);
    short* xnb   = (short*)(ws + OFF_XNB);
    short* cqnb  = (short*)(ws + OFF_CQNB);
    short* ckvnb = (short*)(ws + OFF_CKVNB);
    short* qb    = (short*)(ws + OFF_QB);
    short* kb    = (short*)(ws + OFF_KB);
    short* vbt   = (short*)(ws + OFF_VBT);
    short* aob   = (short*)(ws + OFF_AOB);
    short* xn2b  = (short*)(ws + OFF_XN2B);
    short* gact  = (short*)(ws + OFF_GACT);
    short* eact  = (short*)(ws + OFF_EACT);
    short* wdqT  = (short*)(ws + OFF_WDQT);
    short* wdkvT = (short*)(ws + OFF_WDKVT);
    short* wuqT  = (short*)(ws + OFF_WUQT);
    short* wukvT = (short*)(ws + OFF_WUKVT);
    short* woT   = (short*)(ws + OFF_WOT);
    short* shwgT = (short*)(ws + OFF_SHWGT);
    short* shwuT = (short*)(ws + OFF_SHWUT);
    short* shwdT = (short*)(ws + OFF_SHWDT);
    short* rwgT  = (short*)(ws + OFF_RWGT);
    short* rwuT  = (short*)(ws + OFF_RWUT);
    short* rwdT  = (short*)(ws + OFF_RWDT);

    // 0. weight convert+transpose (bf16 [N][K])
    k_cvt_t<<<dim3(8, 16, 1),  256, 0, stream>>>(w_dq,  wdqT,  512, 256);
    k_cvt_t<<<dim3(5, 16, 1),  256, 0, stream>>>(w_dkv, wdkvT, 512, 160);
    k_cvt_t<<<dim3(24, 8, 1),  256, 0, stream>>>(w_uq,  wuqT,  256, 768);
    k_cvt_t<<<dim3(32, 4, 1),  256, 0, stream>>>(w_ukv, wukvT, 128, 1024);
    k_cvt_t<<<dim3(16, 16, 1), 256, 0, stream>>>(w_o,   woT,   512, 512);
    k_cvt_t<<<dim3(8, 16, 1),  256, 0, stream>>>(sh_wg, shwgT, 512, 256);
    k_cvt_t<<<dim3(8, 16, 1),  256, 0, stream>>>(sh_wu, shwuT, 512, 256);
    k_cvt_t<<<dim3(16, 8, 1),  256, 0, stream>>>(sh_wd, shwdT, 256, 512);
    k_cvt_t<<<dim3(8, 16, 16), 256, 0, stream>>>(r_wg,  rwgT,  512, 256);
    k_cvt_t<<<dim3(8, 16, 16), 256, 0, stream>>>(r_wu,  rwuT,  512, 256);
    k_cvt_t<<<dim3(16, 8, 16), 256, 0, stream>>>(r_wd,  rwdT,  256, 512);

    // 1. input RMSNorm -> bf16
    k_rms<<<Tt, 256, 0, stream>>>(hs, 512, w_innorm, nullptr, xnb, 512, 512);
    // 2. down-projections
    k_mgemm<0><<<dim3(4, 32), 256, 0, stream>>>(xnb, wdqT, cq, nullptr, 256, 512);
    k_mgemm<0><<<dim3(3, 32), 256, 0, stream>>>(xnb, wdkvT, ckv, nullptr, 160, 512);
    // 3. latent norms -> bf16
    k_rms<<<Tt, 256, 0, stream>>>(cq, 256, w_qnorm, nullptr, cqnb, 256, 256);
    k_rms<<<Tt, 256, 0, stream>>>(ckv, 160, w_kvnorm, nullptr, ckvnb, 128, 128);
    // 4. up-projections
    k_mgemm<0><<<dim3(12, 32), 256, 0, stream>>>(cqnb, wuqT, qcr, nullptr, 768, 256);
    k_mgemm<0><<<dim3(16, 32), 256, 0, stream>>>(ckvnb, wukvT, kvb, nullptr, 1024, 128);
    // 5. build q/k/v (RoPE) -> bf16
    k_build_q<<<(16 * 2048 * 96) / 256, 256, 0, stream>>>(qcr, qb);
    k_build_k<<<(16 * 2048 * 96) / 256, 256, 0, stream>>>(kvb, ckv, kb);
    k_build_vt<<<(16 * 64 * 2048) / 256, 256, 0, stream>>>(kvb, vbt);
    // 6. MFMA flash attention
    k_attn<<<512, 256, 0, stream>>>(qb, kb, vbt, aob);
    // 7. output proj + residual
    k_mgemm<1><<<dim3(8, 32), 256, 0, stream>>>(aob, woT, r2, hs, 512, 512);
    // 8. post norm (f32 for router + bf16 for GEMMs)
    k_rms<<<Tt, 256, 0, stream>>>(r2, 512, w_post, xn2, xn2b, 512, 512);
    // 9. shared expert
    k_mgemm<0><<<dim3(4, 32), 256, 0, stream>>>(xn2b, shwgT, g, nullptr, 256, 512);
    k_mgemm<0><<<dim3(4, 32), 256, 0, stream>>>(xn2b, shwuT, u, nullptr, 256, 512);
    k_swiglu<<<Tt, 256, 0, stream>>>(g, u, gact, Tt * 256);
    k_mgemm<1><<<dim3(8, 32), 256, 0, stream>>>(gact, shwdT, oacc, r2, 512, 256);
    // 10. router + MoE
    hipMemsetAsync(ecnt, 0, NEn * sizeof(int), stream);
    k_router<<<Tt, 64, 0, stream>>>(xn2, w_gate, ewt, ecnt, etok);
    k_moe1m<<<dim3(512, 4), 256, 0, stream>>>(xn2b, rwgT, rwuT, ecnt, etok, eact);
    k_moe2m<<<dim3(512, 8), 256, 0, stream>>>(eact, rwdT, ecnt, etok, ewt, oacc);
    // 11. finalize
    k_final<<<(Tt * 512) / 256, 256, 0, stream>>>(oacc, (float*)d_out, Tt * 512);
}

// Round 4
// 537.269 us; speedup vs baseline: 7.7380x; 1.0615x over previous
//
#include <hip/hip_runtime.h>
#include <hip/hip_bf16.h>
#include <math.h>

typedef float f32x4 __attribute__((ext_vector_type(4)));
typedef short s16x8 __attribute__((ext_vector_type(8)));

// ---------------- problem constants ----------------
constexpr int Tt = 4096;
constexpr int NEn = 16;
constexpr float EPSf = 1.1920929e-07f;

__device__ __forceinline__ short f2b(float f) {
    union { __hip_bfloat16 h; short s; } u;
    u.h = __float2bfloat16(f);
    return u.s;
}

// ---------------- workspace layout (float elements, 16-float aligned) ----------------
constexpr size_t alg(size_t x) { return (x + 15) & ~(size_t)15; }
// f32 buffers
constexpr size_t OFF_CQ   = 0;                                   // T*256 f32
constexpr size_t OFF_CKV  = alg(OFF_CQ   + (size_t)Tt * 256);    // T*160 f32
constexpr size_t OFF_QCR  = alg(OFF_CKV  + (size_t)Tt * 160);    // T*768 f32
constexpr size_t OFF_KVB  = alg(OFF_QCR  + (size_t)Tt * 768);    // T*1024 f32
constexpr size_t OFF_R2   = alg(OFF_KVB  + (size_t)Tt * 1024);   // T*512 f32
constexpr size_t OFF_XN2  = alg(OFF_R2   + (size_t)Tt * 512);    // T*512 f32
constexpr size_t OFF_OACC = alg(OFF_XN2  + (size_t)Tt * 512);    // (unused now; kept for layout stability)
constexpr size_t OFF_EWT  = alg(OFF_OACC + (size_t)Tt * 512);    // 16*4096 f32
constexpr size_t OFF_ECNT = alg(OFF_EWT  + (size_t)NEn * Tt);    // ints
constexpr size_t OFF_ETOK = alg(OFF_ECNT + 64);                  // 16*4096 ints
// bf16 buffers (element counts halved into float units)
constexpr size_t OFF_XNB   = alg(OFF_ETOK + (size_t)NEn * Tt);       // T*512 bf16
constexpr size_t OFF_CQNB  = alg(OFF_XNB   + (size_t)Tt * 512 / 2);  // T*256 bf16
constexpr size_t OFF_CKVNB = alg(OFF_CQNB  + (size_t)Tt * 256 / 2);  // T*128 bf16
constexpr size_t OFF_QB    = alg(OFF_CKVNB + (size_t)Tt * 128 / 2);  // 16*2048*96 bf16
constexpr size_t OFF_KB    = alg(OFF_QB    + (size_t)16 * 2048 * 96 / 2);
constexpr size_t OFF_VBT   = alg(OFF_KB    + (size_t)16 * 2048 * 96 / 2); // 16*64*2048 bf16
constexpr size_t OFF_AOB   = alg(OFF_VBT   + (size_t)16 * 64 * 2048 / 2); // T*512 bf16
constexpr size_t OFF_XN2B  = alg(OFF_AOB   + (size_t)Tt * 512 / 2);
constexpr size_t OFF_GACT  = alg(OFF_XN2B  + (size_t)Tt * 512 / 2);  // T*256 bf16
constexpr size_t OFF_EACT  = alg(OFF_GACT  + (size_t)Tt * 256 / 2);  // 16384*256 bf16
// transposed bf16 weights [N][K]
constexpr size_t OFF_WDQT  = alg(OFF_EACT  + (size_t)16384 * 256 / 2);
constexpr size_t OFF_WDKVT = alg(OFF_WDQT  + (size_t)256 * 512 / 2);
constexpr size_t OFF_WUQT  = alg(OFF_WDKVT + (size_t)160 * 512 / 2);
constexpr size_t OFF_WUKVT = alg(OFF_WUQT  + (size_t)768 * 256 / 2);
constexpr size_t OFF_WOT   = alg(OFF_WUKVT + (size_t)1024 * 128 / 2);
constexpr size_t OFF_SHWGT = alg(OFF_WOT   + (size_t)512 * 512 / 2);
constexpr size_t OFF_SHWUT = alg(OFF_SHWGT + (size_t)256 * 512 / 2);
constexpr size_t OFF_SHWDT = alg(OFF_SHWUT + (size_t)256 * 512 / 2);
constexpr size_t OFF_RWGT  = alg(OFF_SHWDT + (size_t)512 * 256 / 2);
constexpr size_t OFF_RWUT  = alg(OFF_RWGT  + (size_t)16 * 256 * 512 / 2);
constexpr size_t OFF_RWDT  = alg(OFF_RWUT  + (size_t)16 * 256 * 512 / 2);

// ---------------- convert + transpose: src f32 [E][K][N] -> dst bf16 [E][N][K] ----------------
__global__ void k_cvt_t(const float* __restrict__ src, short* __restrict__ dst, int K, int N) {
    __shared__ float t[32][33];
    int n0 = blockIdx.x * 32, k0 = blockIdx.y * 32;
    size_t eo = (size_t)blockIdx.z * K * N;
    int c = threadIdx.x & 31, r = threadIdx.x >> 5;
#pragma unroll
    for (int i = 0; i < 4; ++i)
        t[r + 8 * i][c] = src[eo + (size_t)(k0 + r + 8 * i) * N + n0 + c];
    __syncthreads();
#pragma unroll
    for (int i = 0; i < 4; ++i)
        dst[eo + (size_t)(n0 + r + 8 * i) * K + k0 + c] = f2b(t[c][r + 8 * i]);
}

// ---------------- RMSNorm f32 in -> bf16 out (+ optional f32 out) ----------------
__global__ void k_rms(const float* __restrict__ in, int inStride, const float* __restrict__ w,
                      float* __restrict__ outF, short* __restrict__ outB, int outStride, int D) {
    int row = blockIdx.x, tid = threadIdx.x;
    __shared__ float xs[512];
    __shared__ float red[256];
    const float* ip = in + (size_t)row * inStride;
    float ss = 0.f;
    for (int i = tid; i < D; i += 256) { float v = ip[i]; xs[i] = v; ss += v * v; }
    red[tid] = ss; __syncthreads();
    for (int s = 128; s > 0; s >>= 1) { if (tid < s) red[tid] += red[tid + s]; __syncthreads(); }
    float sc = rsqrtf(red[0] / (float)D + EPSf);
    for (int i = tid; i < D; i += 256) {
        float v = xs[i] * sc * w[i];
        outB[(size_t)row * outStride + i] = f2b(v);
        if (outF) outF[(size_t)row * outStride + i] = v;
    }
}

// ---------------- MFMA GEMM: C(f32)[4096][N] = A_b(bf16)[4096][K] @ B (BT bf16 [N][K]) ----------------
template <int EPI>  // 0: plain, 1: + f32 residual
__global__ __launch_bounds__(256)
void k_mgemm(const short* __restrict__ A, const short* __restrict__ BT,
             float* __restrict__ C, const float* __restrict__ add, int N, int K) {
    __shared__ __align__(16) short As[128 * 64];
    __shared__ __align__(16) short Bs[64 * 64];
    int tid = threadIdx.x;
    int w = tid >> 6, l = tid & 63, g = l >> 4, li = l & 15;
    int wm = w >> 1, wn = w & 1;
    int m0 = blockIdx.y * 128, n0 = blockIdx.x * 64;
    f32x4 acc[4][2] = {};
    for (int k0 = 0; k0 < K; k0 += 64) {
        __syncthreads();
#pragma unroll
        for (int p = 0; p < 4; ++p) {
            int flat = p * 256 + tid;
            int row = flat >> 3, ch = flat & 7;
            *(int4*)&As[row * 64 + ((ch ^ (row & 7)) * 8)] =
                *(const int4*)(A + (size_t)(m0 + row) * K + k0 + 8 * ch);
        }
#pragma unroll
        for (int p = 0; p < 2; ++p) {
            int flat = p * 256 + tid;
            int n = flat >> 3, ch = flat & 7;
            int4 v = {0, 0, 0, 0};
            if (n0 + n < N) v = *(const int4*)(BT + (size_t)(n0 + n) * K + k0 + 8 * ch);
            *(int4*)&Bs[n * 64 + ((ch ^ (n & 7)) * 8)] = v;
        }
        __syncthreads();
#pragma unroll
        for (int kc = 0; kc < 2; ++kc) {
            s16x8 af[4], bf[2];
#pragma unroll
            for (int mt = 0; mt < 4; ++mt) {
                int row = wm * 64 + mt * 16 + li;
                af[mt] = *(const s16x8*)&As[row * 64 + (((4 * kc + g) ^ (li & 7)) * 8)];
            }
#pragma unroll
            for (int nt = 0; nt < 2; ++nt) {
                int n = wn * 32 + nt * 16 + li;
                bf[nt] = *(const s16x8*)&Bs[n * 64 + (((4 * kc + g) ^ (li & 7)) * 8)];
            }
#pragma unroll
            for (int mt = 0; mt < 4; ++mt)
#pragma unroll
                for (int nt = 0; nt < 2; ++nt)
                    acc[mt][nt] = __builtin_amdgcn_mfma_f32_16x16x32_bf16(af[mt], bf[nt], acc[mt][nt], 0, 0, 0);
        }
    }
#pragma unroll
    for (int mt = 0; mt < 4; ++mt)
#pragma unroll
        for (int nt = 0; nt < 2; ++nt)
#pragma unroll
            for (int r = 0; r < 4; ++r) {
                int gm = m0 + wm * 64 + mt * 16 + 4 * g + r;
                int gn = n0 + wn * 32 + nt * 16 + li;
                if (gn < N) {
                    float v = acc[mt][nt][r];
                    if (EPI == 1) v += add[(size_t)gm * N + gn];
                    C[(size_t)gm * N + gn] = v;
                }
            }
}

// ---------------- shared expert: gact = silu(x@wg)*(x@wu), bf16 out ----------------
__global__ __launch_bounds__(256)
void k_shexp(const short* __restrict__ X, const short* __restrict__ WGt, const short* __restrict__ WUt,
             short* __restrict__ gact) {
    __shared__ __align__(16) short As[128 * 64];
    __shared__ __align__(16) short Bg[64 * 64];
    __shared__ __align__(16) short Bu[64 * 64];
    int tid = threadIdx.x;
    int w = tid >> 6, l = tid & 63, g = l >> 4, li = l & 15;
    int wm = w >> 1, wn = w & 1;
    int m0 = blockIdx.x * 128, n0 = blockIdx.y * 64;
    f32x4 ag[4][2] = {}, au[4][2] = {};
    for (int k0 = 0; k0 < 512; k0 += 64) {
        __syncthreads();
#pragma unroll
        for (int p = 0; p < 4; ++p) {
            int flat = p * 256 + tid;
            int row = flat >> 3, ch = flat & 7;
            *(int4*)&As[row * 64 + ((ch ^ (row & 7)) * 8)] =
                *(const int4*)(X + (size_t)(m0 + row) * 512 + k0 + 8 * ch);
        }
#pragma unroll
        for (int p = 0; p < 2; ++p) {
            int flat = p * 256 + tid;
            int n = flat >> 3, ch = flat & 7;
            *(int4*)&Bg[n * 64 + ((ch ^ (n & 7)) * 8)] = *(const int4*)(WGt + (size_t)(n0 + n) * 512 + k0 + 8 * ch);
            *(int4*)&Bu[n * 64 + ((ch ^ (n & 7)) * 8)] = *(const int4*)(WUt + (size_t)(n0 + n) * 512 + k0 + 8 * ch);
        }
        __syncthreads();
#pragma unroll
        for (int kc = 0; kc < 2; ++kc) {
            s16x8 af[4], bg[2], bu[2];
#pragma unroll
            for (int mt = 0; mt < 4; ++mt) {
                int row = wm * 64 + mt * 16 + li;
                af[mt] = *(const s16x8*)&As[row * 64 + (((4 * kc + g) ^ (li & 7)) * 8)];
            }
#pragma unroll
            for (int nt = 0; nt < 2; ++nt) {
                int n = wn * 32 + nt * 16 + li;
                bg[nt] = *(const s16x8*)&Bg[n * 64 + (((4 * kc + g) ^ (li & 7)) * 8)];
                bu[nt] = *(const s16x8*)&Bu[n * 64 + (((4 * kc + g) ^ (li & 7)) * 8)];
            }
#pragma unroll
            for (int mt = 0; mt < 4; ++mt)
#pragma unroll
                for (int nt = 0; nt < 2; ++nt) {
                    ag[mt][nt] = __builtin_amdgcn_mfma_f32_16x16x32_bf16(af[mt], bg[nt], ag[mt][nt], 0, 0, 0);
                    au[mt][nt] = __builtin_amdgcn_mfma_f32_16x16x32_bf16(af[mt], bu[nt], au[mt][nt], 0, 0, 0);
                }
        }
    }
#pragma unroll
    for (int mt = 0; mt < 4; ++mt)
#pragma unroll
        for (int nt = 0; nt < 2; ++nt)
#pragma unroll
            for (int r = 0; r < 4; ++r) {
                int gm = m0 + wm * 64 + mt * 16 + 4 * g + r;
                int gn = n0 + wn * 32 + nt * 16 + li;
                float gv = ag[mt][nt][r], uv = au[mt][nt][r];
                gact[(size_t)gm * 256 + gn] = f2b(gv / (1.f + __expf(-gv)) * uv);
            }
}

// ---------------- q build: split + RoPE -> bf16 ----------------
__global__ void k_build_q(const float* __restrict__ qcr, short* __restrict__ qb) {
    int gid = blockIdx.x * 256 + threadIdx.x;   // 16*2048*96
    int d = gid % 96;
    int rs = gid / 96;
    int srow = rs & 2047;
    int bh = rs >> 11;
    int b = bh >> 3, h = bh & 7;
    int t = b * 2048 + srow;
    const float* src = qcr + (size_t)t * 768 + h * 96;
    float val;
    if (d < 64) {
        val = src[d];
    } else {
        int d2 = d - 64;
        int fi = d2 & 15;
        float ang = (float)srow * __expf(-((float)(2 * fi) / 32.f) * 9.210340371976184f);
        float s, c; __sincosf(ang, &s, &c);
        float x = src[64 + d2];
        float r = (d2 < 16) ? -src[64 + d2 + 16] : src[64 + d2 - 16];
        val = x * c + r * s;
    }
    qb[gid] = f2b(val);
}

// ---------------- k build: split + RoPE(k_r broadcast) -> bf16 ----------------
__global__ void k_build_k(const float* __restrict__ kvb, const float* __restrict__ ckv,
                          short* __restrict__ kb) {
    int gid = blockIdx.x * 256 + threadIdx.x;   // 16*2048*96
    int d = gid % 96;
    int rs = gid / 96;
    int srow = rs & 2047;
    int bh = rs >> 11;
    int b = bh >> 3, h = bh & 7;
    int t = b * 2048 + srow;
    float val;
    if (d < 64) {
        val = kvb[(size_t)t * 1024 + h * 128 + d];
    } else {
        int d2 = d - 64;
        int fi = d2 & 15;
        float ang = (float)srow * __expf(-((float)(2 * fi) / 32.f) * 9.210340371976184f);
        float s, c; __sincosf(ang, &s, &c);
        float x = ckv[(size_t)t * 160 + 128 + d2];
        float r = (d2 < 16) ? -ckv[(size_t)t * 160 + 128 + d2 + 16]
                            :  ckv[(size_t)t * 160 + 128 + d2 - 16];
        val = x * c + r * s;
    }
    kb[gid] = f2b(val);
}

// ---------------- v build transposed: vbt[bh][dim64][key2048] bf16 ----------------
__global__ void k_build_vt(const float* __restrict__ kvb, short* __restrict__ vbt) {
    int gid = blockIdx.x * 256 + threadIdx.x;   // 16*64*2048
    int key = gid & 2047;
    int dim = (gid >> 11) & 63;
    int bh = gid >> 17;
    int b = bh >> 3, h = bh & 7;
    vbt[gid] = f2b(kvb[(size_t)(b * 2048 + key) * 1024 + h * 128 + 64 + dim]);
}

// ---------------- MFMA flash attention: 4 waves/block, wave = 16 q cols ----------------
__global__ __launch_bounds__(256)
void k_attn(const short* __restrict__ qb, const short* __restrict__ kb,
            const short* __restrict__ vbt, short* __restrict__ ao) {
    __shared__ __align__(16) short Ks[64 * 96];
    __shared__ __align__(16) short Vs[64 * 64];
    int tid = threadIdx.x;
    int w = tid >> 6, l = tid & 63, g = l >> 4, li = l & 15;
    int bh = blockIdx.x >> 5, qt = blockIdx.x & 31;
    int b = bh >> 3, h = bh & 7;
    int qcol = qt * 64 + w * 16 + li;
    const float scale = 0.10206207261596575f;  // 1/sqrt(96)

    s16x8 qf[3];
    const short* qp = qb + (size_t)(bh * 2048 + qcol) * 96;
#pragma unroll
    for (int c = 0; c < 3; ++c) qf[c] = *(const s16x8*)(qp + 32 * c + 8 * g);

    f32x4 o[4] = {};
    float m = -INFINITY, lsum = 0.f;
    const short* kbase = kb + (size_t)bh * 2048 * 96;
    const short* vbase = vbt + (size_t)bh * 64 * 2048;

    for (int k0 = 0; k0 < 2048; k0 += 64) {
        __syncthreads();
#pragma unroll
        for (int p = 0; p < 3; ++p) {
            int flat = p * 256 + tid;
            int key = flat / 12, u = flat % 12;
            *(int4*)&Ks[key * 96 + 8 * u] = *(const int4*)(kbase + (size_t)(k0 + key) * 96 + 8 * u);
        }
#pragma unroll
        for (int p = 0; p < 2; ++p) {
            int flat = p * 256 + tid;
            int dim = flat >> 3, kc8 = flat & 7;
            int4 v = *(const int4*)(vbase + (size_t)dim * 2048 + k0 + 8 * kc8);
            int sw = dim & 15;
            *(int2*)&Vs[dim * 64 + (((2 * kc8) ^ sw) * 4)]     = make_int2(v.x, v.y);
            *(int2*)&Vs[dim * 64 + (((2 * kc8 + 1) ^ sw) * 4)] = make_int2(v.z, v.w);
        }
        __syncthreads();

        // S^T[key][q] = K · Q^T
        f32x4 s[4];
#pragma unroll
        for (int kt = 0; kt < 4; ++kt) {
            f32x4 acc = {};
#pragma unroll
            for (int c = 0; c < 3; ++c) {
                s16x8 kf = *(const s16x8*)&Ks[(kt * 16 + li) * 96 + 32 * c + 8 * g];
                acc = __builtin_amdgcn_mfma_f32_16x16x32_bf16(kf, qf[c], acc, 0, 0, 0);
            }
#pragma unroll
            for (int r = 0; r < 4; ++r) acc[r] *= scale;
            s[kt] = acc;
        }
        // per-q max over 64 keys
        float pm = -INFINITY;
#pragma unroll
        for (int kt = 0; kt < 4; ++kt)
#pragma unroll
            for (int r = 0; r < 4; ++r) pm = fmaxf(pm, s[kt][r]);
        pm = fmaxf(pm, __shfl_xor(pm, 16));
        pm = fmaxf(pm, __shfl_xor(pm, 32));
        float mn = fmaxf(m, pm);
        float corr = __expf(m - mn);
        float ps = 0.f;
#pragma unroll
        for (int kt = 0; kt < 4; ++kt)
#pragma unroll
            for (int r = 0; r < 4; ++r) { float p = __expf(s[kt][r] - mn); s[kt][r] = p; ps += p; }
        ps += __shfl_xor(ps, 16);
        ps += __shfl_xor(ps, 32);
        lsum = lsum * corr + ps;
        m = mn;
#pragma unroll
        for (int dt = 0; dt < 4; ++dt)
#pragma unroll
            for (int r = 0; r < 4; ++r) o[dt][r] *= corr;

        // P^T fragments (lane-local)
        s16x8 pf[2];
#pragma unroll
        for (int kc = 0; kc < 2; ++kc) {
            s16x8 t;
#pragma unroll
            for (int r = 0; r < 4; ++r) { t[r] = f2b(s[2 * kc][r]); t[4 + r] = f2b(s[2 * kc + 1][r]); }
            pf[kc] = t;
        }
        // O^T += V^T · P^T
#pragma unroll
        for (int dt = 0; dt < 4; ++dt) {
            int dim = dt * 16 + li;
#pragma unroll
            for (int kc = 0; kc < 2; ++kc) {
                int2 a0 = *(const int2*)&Vs[dim * 64 + (((8 * kc + g) ^ li) * 4)];
                int2 a1 = *(const int2*)&Vs[dim * 64 + (((8 * kc + 4 + g) ^ li) * 4)];
                union { s16x8 v; int i[4]; } vf;
                vf.i[0] = a0.x; vf.i[1] = a0.y; vf.i[2] = a1.x; vf.i[3] = a1.y;
                o[dt] = __builtin_amdgcn_mfma_f32_16x16x32_bf16(vf.v, pf[kc], o[dt], 0, 0, 0);
            }
        }
    }
    float inv = 1.f / lsum;
    short* op = ao + (size_t)(b * 2048 + qcol) * 512 + h * 64;
#pragma unroll
    for (int dt = 0; dt < 4; ++dt)
#pragma unroll
        for (int r = 0; r < 4; ++r)
            op[dt * 16 + 4 * g + r] = f2b(o[dt][r] * inv);
}

// ---------------- router: wave-parallel scoring + top-4 ----------------
__global__ __launch_bounds__(256)
void k_router(const float* __restrict__ xn2, const float* __restrict__ wg,
              float* __restrict__ ewt, int* __restrict__ ecnt, int* __restrict__ etok) {
    int wid = threadIdx.x >> 6, lane = threadIdx.x & 63;
    int t = blockIdx.x * 4 + wid;
    int e = lane & 15, chunk = lane >> 4;          // 16 experts x 4 k-chunks
    const float* xp = xn2 + (size_t)t * 512 + chunk * 128;
    const float* wp = wg + (size_t)chunk * 128 * 16 + e;
    float s = 0.f;
#pragma unroll 16
    for (int k = 0; k < 128; ++k) s = fmaf(xp[k], wp[(size_t)k * 16], s);
    s += __shfl_xor(s, 16);
    s += __shfl_xor(s, 32);
    float sc = 1.f / (1.f + expf(-s));             // all 4 replicas of expert e hold sc
    unsigned sel = 0;
    float tw[4]; int ti[4];
#pragma unroll
    for (int kk = 0; kk < 4; ++kk) {
        float cand = ((sel >> e) & 1u) ? -1e30f : sc;
        float mx = cand;
        mx = fmaxf(mx, __shfl_xor(mx, 1));
        mx = fmaxf(mx, __shfl_xor(mx, 2));
        mx = fmaxf(mx, __shfl_xor(mx, 4));
        mx = fmaxf(mx, __shfl_xor(mx, 8));
        unsigned long long msk = __ballot(cand == mx);
        int bi = (__ffsll(msk) - 1) & 15;          // lowest lane => lowest expert idx (tie-break matches top_k)
        tw[kk] = mx; ti[kk] = bi;
        sel |= 1u << bi;
    }
    if (lane == 0) {
        float inv = 1.f / (tw[0] + tw[1] + tw[2] + tw[3]);
#pragma unroll
        for (int kk = 0; kk < 4; ++kk) {
            int slot = atomicAdd(&ecnt[ti[kk]], 1);
            etok[ti[kk] * 4096 + slot] = t * 4 + kk;
            ewt[ti[kk] * 4096 + slot] = tw[kk] * inv;
        }
    }
}

// ---------------- MoE stage 1 (MFMA): eact = silu(x@wg)*(x@wu) ----------------
__global__ __launch_bounds__(256)
void k_moe1m(const short* __restrict__ X, const short* __restrict__ WGt, const short* __restrict__ WUt,
             const int* __restrict__ ecnt, const int* __restrict__ etok, short* __restrict__ eact) {
    int e = blockIdx.x >> 5, mt128 = blockIdx.x & 31;
    int cnt = ecnt[e];
    int base = mt128 * 128;
    if (base >= cnt) return;
    int rows = min(128, cnt - base);
    int n0 = blockIdx.y * 64;
    __shared__ __align__(16) short As[128 * 64];
    __shared__ __align__(16) short Bg[64 * 64];
    __shared__ __align__(16) short Bu[64 * 64];
    __shared__ int toks[128];
    int tid = threadIdx.x;
    if (tid < 128) toks[tid] = (tid < rows) ? etok[e * 4096 + base + tid] : -1;
    __syncthreads();
    int w = tid >> 6, l = tid & 63, g = l >> 4, li = l & 15;
    int wm = w >> 1, wn = w & 1;
    const short* wgp = WGt + (size_t)e * 256 * 512;
    const short* wup = WUt + (size_t)e * 256 * 512;
    f32x4 ag[4][2] = {}, au[4][2] = {};
    for (int k0 = 0; k0 < 512; k0 += 64) {
        __syncthreads();
#pragma unroll
        for (int p = 0; p < 4; ++p) {
            int flat = p * 256 + tid;
            int row = flat >> 3, ch = flat & 7;
            int tk = toks[row];
            int4 v = {0, 0, 0, 0};
            if (tk >= 0) v = *(const int4*)(X + (size_t)(tk >> 2) * 512 + k0 + 8 * ch);
            *(int4*)&As[row * 64 + ((ch ^ (row & 7)) * 8)] = v;
        }
#pragma unroll
        for (int p = 0; p < 2; ++p) {
            int flat = p * 256 + tid;
            int n = flat >> 3, ch = flat & 7;
            *(int4*)&Bg[n * 64 + ((ch ^ (n & 7)) * 8)] = *(const int4*)(wgp + (size_t)(n0 + n) * 512 + k0 + 8 * ch);
            *(int4*)&Bu[n * 64 + ((ch ^ (n & 7)) * 8)] = *(const int4*)(wup + (size_t)(n0 + n) * 512 + k0 + 8 * ch);
        }
        __syncthreads();
#pragma unroll
        for (int kc = 0; kc < 2; ++kc) {
            s16x8 af[4], bg[2], bu[2];
#pragma unroll
            for (int mt = 0; mt < 4; ++mt) {
                int row = wm * 64 + mt * 16 + li;
                af[mt] = *(const s16x8*)&As[row * 64 + (((4 * kc + g) ^ (li & 7)) * 8)];
            }
#pragma unroll
            for (int nt = 0; nt < 2; ++nt) {
                int n = wn * 32 + nt * 16 + li;
                bg[nt] = *(const s16x8*)&Bg[n * 64 + (((4 * kc + g) ^ (li & 7)) * 8)];
                bu[nt] = *(const s16x8*)&Bu[n * 64 + (((4 * kc + g) ^ (li & 7)) * 8)];
            }
#pragma unroll
            for (int mt = 0; mt < 4; ++mt)
#pragma unroll
                for (int nt = 0; nt < 2; ++nt) {
                    ag[mt][nt] = __builtin_amdgcn_mfma_f32_16x16x32_bf16(af[mt], bg[nt], ag[mt][nt], 0, 0, 0);
                    au[mt][nt] = __builtin_amdgcn_mfma_f32_16x16x32_bf16(af[mt], bu[nt], au[mt][nt], 0, 0, 0);
                }
        }
    }
#pragma unroll
    for (int mt = 0; mt < 4; ++mt)
#pragma unroll
        for (int nt = 0; nt < 2; ++nt)
#pragma unroll
            for (int r = 0; r < 4; ++r) {
                int local = wm * 64 + mt * 16 + 4 * g + r;
                if (local < rows) {
                    int entry = toks[local];
                    int gn = n0 + wn * 32 + nt * 16 + li;
                    float gv = ag[mt][nt][r], uv = au[mt][nt][r];
                    eact[(size_t)entry * 256 + gn] = f2b(gv / (1.f + __expf(-gv)) * uv);
                }
            }
}

// ---------------- MoE stage 2 (MFMA): out += w * (eact @ wd) ----------------
__global__ __launch_bounds__(256)
void k_moe2m(const short* __restrict__ EA, const short* __restrict__ WDt,
             const int* __restrict__ ecnt, const int* __restrict__ etok,
             const float* __restrict__ ewt, float* __restrict__ oacc) {
    int e = blockIdx.x >> 5, mt128 = blockIdx.x & 31;
    int cnt = ecnt[e];
    int base = mt128 * 128;
    if (base >= cnt) return;
    int rows = min(128, cnt - base);
    int n0 = blockIdx.y * 64;
    __shared__ __align__(16) short As[128 * 64];
    __shared__ __align__(16) short Bs[64 * 64];
    __shared__ int toks[128];
    __shared__ float wts[128];
    int tid = threadIdx.x;
    if (tid < 128) {
        toks[tid] = (tid < rows) ? etok[e * 4096 + base + tid] : -1;
        wts[tid]  = (tid < rows) ? ewt[e * 4096 + base + tid] : 0.f;
    }
    __syncthreads();
    int w = tid >> 6, l = tid & 63, g = l >> 4, li = l & 15;
    int wm = w >> 1, wn = w & 1;
    const short* wdp = WDt + (size_t)e * 512 * 256;
    f32x4 acc[4][2] = {};
    for (int k0 = 0; k0 < 256; k0 += 64) {
        __syncthreads();
#pragma unroll
        for (int p = 0; p < 4; ++p) {
            int flat = p * 256 + tid;
            int row = flat >> 3, ch = flat & 7;
            int tk = toks[row];
            int4 v = {0, 0, 0, 0};
            if (tk >= 0) v = *(const int4*)(EA + (size_t)tk * 256 + k0 + 8 * ch);
            *(int4*)&As[row * 64 + ((ch ^ (row & 7)) * 8)] = v;
        }
#pragma unroll
        for (int p = 0; p < 2; ++p) {
            int flat = p * 256 + tid;
            int n = flat >> 3, ch = flat & 7;
            *(int4*)&Bs[n * 64 + ((ch ^ (n & 7)) * 8)] = *(const int4*)(wdp + (size_t)(n0 + n) * 256 + k0 + 8 * ch);
        }
        __syncthreads();
#pragma unroll
        for (int kc = 0; kc < 2; ++kc) {
            s16x8 af[4], bf[2];
#pragma unroll
            for (int mt = 0; mt < 4; ++mt) {
                int row = wm * 64 + mt * 16 + li;
                af[mt] = *(const s16x8*)&As[row * 64 + (((4 * kc + g) ^ (li & 7)) * 8)];
            }
#pragma unroll
            for (int nt = 0; nt < 2; ++nt) {
                int n = wn * 32 + nt * 16 + li;
                bf[nt] = *(const s16x8*)&Bs[n * 64 + (((4 * kc + g) ^ (li & 7)) * 8)];
            }
#pragma unroll
            for (int mt = 0; mt < 4; ++mt)
#pragma unroll
                for (int nt = 0; nt < 2; ++nt)
                    acc[mt][nt] = __builtin_amdgcn_mfma_f32_16x16x32_bf16(af[mt], bf[nt], acc[mt][nt], 0, 0, 0);
        }
    }
#pragma unroll
    for (int mt = 0; mt < 4; ++mt)
#pragma unroll
        for (int nt = 0; nt < 2; ++nt)
#pragma unroll
            for (int r = 0; r < 4; ++r) {
                int local = wm * 64 + mt * 16 + 4 * g + r;
                if (local < rows) {
                    int tok = toks[local] >> 2;
                    int gn = n0 + wn * 32 + nt * 16 + li;
                    atomicAdd(&oacc[(size_t)tok * 512 + gn], acc[mt][nt][r] * wts[local]);
                }
            }
}

// ---------------- host launcher ----------------
extern "C" void kernel_launch(void* const* d_in, const int* in_sizes, int n_in,
                              void* d_out, int out_size, void* d_ws, size_t ws_size,
                              hipStream_t stream) {
    const float* hs       = (const float*)d_in[0];
    const float* w_innorm = (const float*)d_in[1];
    const float* w_dq     = (const float*)d_in[2];
    const float* w_qnorm  = (const float*)d_in[3];
    const float* w_uq     = (const float*)d_in[4];
    const float* w_dkv    = (const float*)d_in[5];
    const float* w_kvnorm = (const float*)d_in[6];
    const float* w_ukv    = (const float*)d_in[7];
    const float* w_o      = (const float*)d_in[8];
    const float* w_post   = (const float*)d_in[9];
    const float* w_gate   = (const float*)d_in[10];
    const float* sh_wg    = (const float*)d_in[11];
    const float* sh_wu    = (const float*)d_in[12];
    const float* sh_wd    = (const float*)d_in[13];
    const float* r_wg     = (const float*)d_in[14];
    const float* r_wu     = (const float*)d_in[15];
    const float* r_wd     = (const float*)d_in[16];

    float* ws   = (float*)d_ws;
    float* cq   = ws + OFF_CQ;
    float* ckv  = ws + OFF_CKV;
    float* qcr  = ws + OFF_QCR;
    float* kvb  = ws + OFF_KVB;
    float* r2   = ws + OFF_R2;
    float* xn2  = ws + OFF_XN2;
    float* ewt  = ws + OFF_EWT;
    int*   ecnt = (int*)(ws + OFF_ECNT);
    int*   etok = (int*)(ws + OFF_ETOK);
    short* xnb   = (short*)(ws + OFF_XNB);
    short* cqnb  = (short*)(ws + OFF_CQNB);
    short* ckvnb = (short*)(ws + OFF_CKVNB);
    short* qb    = (short*)(ws + OFF_QB);
    short* kb    = (short*)(ws + OFF_KB);
    short* vbt   = (short*)(ws + OFF_VBT);
    short* aob   = (short*)(ws + OFF_AOB);
    short* xn2b  = (short*)(ws + OFF_XN2B);
    short* gact  = (short*)(ws + OFF_GACT);
    short* eact  = (short*)(ws + OFF_EACT);
    short* wdqT  = (short*)(ws + OFF_WDQT);
    short* wdkvT = (short*)(ws + OFF_WDKVT);
    short* wuqT  = (short*)(ws + OFF_WUQT);
    short* wukvT = (short*)(ws + OFF_WUKVT);
    short* woT   = (short*)(ws + OFF_WOT);
    short* shwgT = (short*)(ws + OFF_SHWGT);
    short* shwuT = (short*)(ws + OFF_SHWUT);
    short* shwdT = (short*)(ws + OFF_SHWDT);
    short* rwgT  = (short*)(ws + OFF_RWGT);
    short* rwuT  = (short*)(ws + OFF_RWUT);
    short* rwdT  = (short*)(ws + OFF_RWDT);

    float* outF = (float*)d_out;   // final accumulator lives directly in d_out

    // 0. weight convert+transpose (bf16 [N][K])
    k_cvt_t<<<dim3(8, 16, 1),  256, 0, stream>>>(w_dq,  wdqT,  512, 256);
    k_cvt_t<<<dim3(5, 16, 1),  256, 0, stream>>>(w_dkv, wdkvT, 512, 160);
    k_cvt_t<<<dim3(24, 8, 1),  256, 0, stream>>>(w_uq,  wuqT,  256, 768);
    k_cvt_t<<<dim3(32, 4, 1),  256, 0, stream>>>(w_ukv, wukvT, 128, 1024);
    k_cvt_t<<<dim3(16, 16, 1), 256, 0, stream>>>(w_o,   woT,   512, 512);
    k_cvt_t<<<dim3(8, 16, 1),  256, 0, stream>>>(sh_wg, shwgT, 512, 256);
    k_cvt_t<<<dim3(8, 16, 1),  256, 0, stream>>>(sh_wu, shwuT, 512, 256);
    k_cvt_t<<<dim3(16, 8, 1),  256, 0, stream>>>(sh_wd, shwdT, 256, 512);
    k_cvt_t<<<dim3(8, 16, 16), 256, 0, stream>>>(r_wg,  rwgT,  512, 256);
    k_cvt_t<<<dim3(8, 16, 16), 256, 0, stream>>>(r_wu,  rwuT,  512, 256);
    k_cvt_t<<<dim3(16, 8, 16), 256, 0, stream>>>(r_wd,  rwdT,  256, 512);

    // 1. input RMSNorm -> bf16
    k_rms<<<Tt, 256, 0, stream>>>(hs, 512, w_innorm, nullptr, xnb, 512, 512);
    // 2. down-projections
    k_mgemm<0><<<dim3(4, 32), 256, 0, stream>>>(xnb, wdqT, cq, nullptr, 256, 512);
    k_mgemm<0><<<dim3(3, 32), 256, 0, stream>>>(xnb, wdkvT, ckv, nullptr, 160, 512);
    // 3. latent norms -> bf16
    k_rms<<<Tt, 256, 0, stream>>>(cq, 256, w_qnorm, nullptr, cqnb, 256, 256);
    k_rms<<<Tt, 256, 0, stream>>>(ckv, 160, w_kvnorm, nullptr, ckvnb, 128, 128);
    // 4. up-projections
    k_mgemm<0><<<dim3(12, 32), 256, 0, stream>>>(cqnb, wuqT, qcr, nullptr, 768, 256);
    k_mgemm<0><<<dim3(16, 32), 256, 0, stream>>>(ckvnb, wukvT, kvb, nullptr, 1024, 128);
    // 5. build q/k/v (RoPE) -> bf16
    k_build_q<<<(16 * 2048 * 96) / 256, 256, 0, stream>>>(qcr, qb);
    k_build_k<<<(16 * 2048 * 96) / 256, 256, 0, stream>>>(kvb, ckv, kb);
    k_build_vt<<<(16 * 64 * 2048) / 256, 256, 0, stream>>>(kvb, vbt);
    // 6. MFMA flash attention
    k_attn<<<512, 256, 0, stream>>>(qb, kb, vbt, aob);
    // 7. output proj + residual
    k_mgemm<1><<<dim3(8, 32), 256, 0, stream>>>(aob, woT, r2, hs, 512, 512);
    // 8. post norm (f32 for router + bf16 for GEMMs)
    k_rms<<<Tt, 256, 0, stream>>>(r2, 512, w_post, xn2, xn2b, 512, 512);
    // 9. shared expert (fused dual-GEMM + swiglu) then down-proj + residual into d_out
    k_shexp<<<dim3(32, 4), 256, 0, stream>>>(xn2b, shwgT, shwuT, gact);
    k_mgemm<1><<<dim3(8, 32), 256, 0, stream>>>(gact, shwdT, outF, r2, 512, 256);
    // 10. router + MoE (atomic accumulate into d_out)
    hipMemsetAsync(ecnt, 0, NEn * sizeof(int), stream);
    k_router<<<Tt / 4, 256, 0, stream>>>(xn2, w_gate, ewt, ecnt, etok);
    k_moe1m<<<dim3(512, 4), 256, 0, stream>>>(xn2b, rwgT, rwuT, ecnt, etok, eact);
    k_moe2m<<<dim3(512, 8), 256, 0, stream>>>(eact, rwdT, ecnt, etok, ewt, outF);
}

// Round 5
// 347.540 us; speedup vs baseline: 11.9623x; 1.5459x over previous
//
#include <hip/hip_runtime.h>
#include <hip/hip_bf16.h>
#include <math.h>

typedef float f32x4 __attribute__((ext_vector_type(4)));
typedef short s16x8 __attribute__((ext_vector_type(8)));

// ---------------- problem constants ----------------
constexpr int Tt = 4096;
constexpr int NEn = 16;
constexpr float EPSf = 1.1920929e-07f;

__device__ __forceinline__ short f2b(float f) {
    union { __hip_bfloat16 h; short s; } u;
    u.h = __float2bfloat16(f);
    return u.s;
}

// ---------------- workspace layout (float elements, 16-float aligned) ----------------
constexpr size_t alg(size_t x) { return (x + 15) & ~(size_t)15; }
// f32 buffers
constexpr size_t OFF_CQ   = 0;                                   // T*256 f32
constexpr size_t OFF_CKV  = alg(OFF_CQ   + (size_t)Tt * 256);    // T*160 f32
constexpr size_t OFF_QCR  = alg(OFF_CKV  + (size_t)Tt * 160);    // T*768 f32
constexpr size_t OFF_KVB  = alg(OFF_QCR  + (size_t)Tt * 768);    // T*1024 f32
constexpr size_t OFF_R2   = alg(OFF_KVB  + (size_t)Tt * 1024);   // T*512 f32
constexpr size_t OFF_XN2  = alg(OFF_R2   + (size_t)Tt * 512);    // T*512 f32
constexpr size_t OFF_TOKE = alg(OFF_XN2  + (size_t)Tt * 512);    // T*4 ints (top-4 experts)
constexpr size_t OFF_TOKW = alg(OFF_TOKE + (size_t)Tt * 4);      // T*4 f32 (top-4 weights)
constexpr size_t OFF_EWT  = alg(OFF_TOKW + (size_t)Tt * 4);      // 16*4096 f32
constexpr size_t OFF_ECNT = alg(OFF_EWT  + (size_t)NEn * Tt);    // ints
constexpr size_t OFF_ETOK = alg(OFF_ECNT + 64);                  // 16*4096 ints
// bf16 buffers (element counts halved into float units)
constexpr size_t OFF_XNB   = alg(OFF_ETOK + (size_t)NEn * Tt);       // T*512 bf16
constexpr size_t OFF_CQNB  = alg(OFF_XNB   + (size_t)Tt * 512 / 2);  // T*256 bf16
constexpr size_t OFF_CKVNB = alg(OFF_CQNB  + (size_t)Tt * 256 / 2);  // T*128 bf16
constexpr size_t OFF_QB    = alg(OFF_CKVNB + (size_t)Tt * 128 / 2);  // 16*2048*96 bf16
constexpr size_t OFF_KB    = alg(OFF_QB    + (size_t)16 * 2048 * 96 / 2);
constexpr size_t OFF_VBT   = alg(OFF_KB    + (size_t)16 * 2048 * 96 / 2); // 16*64*2048 bf16
constexpr size_t OFF_AOB   = alg(OFF_VBT   + (size_t)16 * 64 * 2048 / 2); // T*512 bf16
constexpr size_t OFF_XN2B  = alg(OFF_AOB   + (size_t)Tt * 512 / 2);
constexpr size_t OFF_GACT  = alg(OFF_XN2B  + (size_t)Tt * 512 / 2);  // T*256 bf16
constexpr size_t OFF_EACT  = alg(OFF_GACT  + (size_t)Tt * 256 / 2);  // 16384*256 bf16
// transposed bf16 weights [N][K]
constexpr size_t OFF_WDQT  = alg(OFF_EACT  + (size_t)16384 * 256 / 2);
constexpr size_t OFF_WDKVT = alg(OFF_WDQT  + (size_t)256 * 512 / 2);
constexpr size_t OFF_WUQT  = alg(OFF_WDKVT + (size_t)160 * 512 / 2);
constexpr size_t OFF_WUKVT = alg(OFF_WUQT  + (size_t)768 * 256 / 2);
constexpr size_t OFF_WOT   = alg(OFF_WUKVT + (size_t)1024 * 128 / 2);
constexpr size_t OFF_SHWGT = alg(OFF_WOT   + (size_t)512 * 512 / 2);
constexpr size_t OFF_SHWUT = alg(OFF_SHWGT + (size_t)256 * 512 / 2);
constexpr size_t OFF_SHWDT = alg(OFF_SHWUT + (size_t)256 * 512 / 2);
constexpr size_t OFF_RWGT  = alg(OFF_SHWDT + (size_t)512 * 256 / 2);
constexpr size_t OFF_RWUT  = alg(OFF_RWGT  + (size_t)16 * 256 * 512 / 2);
constexpr size_t OFF_RWDT  = alg(OFF_RWUT  + (size_t)16 * 256 * 512 / 2);

// ---------------- convert + transpose: src f32 [E][K][N] -> dst bf16 [E][N][K] ----------------
__global__ void k_cvt_t(const float* __restrict__ src, short* __restrict__ dst, int K, int N) {
    __shared__ float t[32][33];
    int n0 = blockIdx.x * 32, k0 = blockIdx.y * 32;
    size_t eo = (size_t)blockIdx.z * K * N;
    int c = threadIdx.x & 31, r = threadIdx.x >> 5;
#pragma unroll
    for (int i = 0; i < 4; ++i)
        t[r + 8 * i][c] = src[eo + (size_t)(k0 + r + 8 * i) * N + n0 + c];
    __syncthreads();
#pragma unroll
    for (int i = 0; i < 4; ++i)
        dst[eo + (size_t)(n0 + r + 8 * i) * K + k0 + c] = f2b(t[c][r + 8 * i]);
}

// ---------------- RMSNorm f32 in -> bf16 out (+ optional f32 out) ----------------
__global__ void k_rms(const float* __restrict__ in, int inStride, const float* __restrict__ w,
                      float* __restrict__ outF, short* __restrict__ outB, int outStride, int D) {
    int row = blockIdx.x, tid = threadIdx.x;
    __shared__ float xs[512];
    __shared__ float red[256];
    const float* ip = in + (size_t)row * inStride;
    float ss = 0.f;
    for (int i = tid; i < D; i += 256) { float v = ip[i]; xs[i] = v; ss += v * v; }
    red[tid] = ss; __syncthreads();
    for (int s = 128; s > 0; s >>= 1) { if (tid < s) red[tid] += red[tid + s]; __syncthreads(); }
    float sc = rsqrtf(red[0] / (float)D + EPSf);
    for (int i = tid; i < D; i += 256) {
        float v = xs[i] * sc * w[i];
        outB[(size_t)row * outStride + i] = f2b(v);
        if (outF) outF[(size_t)row * outStride + i] = v;
    }
}

// ---------------- MFMA GEMM: C(f32)[4096][N] = A_b(bf16)[4096][K] @ B (BT bf16 [N][K]) ----------------
template <int EPI>  // 0: plain, 1: + f32 residual
__global__ __launch_bounds__(256)
void k_mgemm(const short* __restrict__ A, const short* __restrict__ BT,
             float* __restrict__ C, const float* __restrict__ add, int N, int K) {
    __shared__ __align__(16) short As[128 * 64];
    __shared__ __align__(16) short Bs[64 * 64];
    int tid = threadIdx.x;
    int w = tid >> 6, l = tid & 63, g = l >> 4, li = l & 15;
    int wm = w >> 1, wn = w & 1;
    int m0 = blockIdx.y * 128, n0 = blockIdx.x * 64;
    f32x4 acc[4][2] = {};
    for (int k0 = 0; k0 < K; k0 += 64) {
        __syncthreads();
#pragma unroll
        for (int p = 0; p < 4; ++p) {
            int flat = p * 256 + tid;
            int row = flat >> 3, ch = flat & 7;
            *(int4*)&As[row * 64 + ((ch ^ (row & 7)) * 8)] =
                *(const int4*)(A + (size_t)(m0 + row) * K + k0 + 8 * ch);
        }
#pragma unroll
        for (int p = 0; p < 2; ++p) {
            int flat = p * 256 + tid;
            int n = flat >> 3, ch = flat & 7;
            int4 v = {0, 0, 0, 0};
            if (n0 + n < N) v = *(const int4*)(BT + (size_t)(n0 + n) * K + k0 + 8 * ch);
            *(int4*)&Bs[n * 64 + ((ch ^ (n & 7)) * 8)] = v;
        }
        __syncthreads();
#pragma unroll
        for (int kc = 0; kc < 2; ++kc) {
            s16x8 af[4], bf[2];
#pragma unroll
            for (int mt = 0; mt < 4; ++mt) {
                int row = wm * 64 + mt * 16 + li;
                af[mt] = *(const s16x8*)&As[row * 64 + (((4 * kc + g) ^ (li & 7)) * 8)];
            }
#pragma unroll
            for (int nt = 0; nt < 2; ++nt) {
                int n = wn * 32 + nt * 16 + li;
                bf[nt] = *(const s16x8*)&Bs[n * 64 + (((4 * kc + g) ^ (li & 7)) * 8)];
            }
#pragma unroll
            for (int mt = 0; mt < 4; ++mt)
#pragma unroll
                for (int nt = 0; nt < 2; ++nt)
                    acc[mt][nt] = __builtin_amdgcn_mfma_f32_16x16x32_bf16(af[mt], bf[nt], acc[mt][nt], 0, 0, 0);
        }
    }
#pragma unroll
    for (int mt = 0; mt < 4; ++mt)
#pragma unroll
        for (int nt = 0; nt < 2; ++nt)
#pragma unroll
            for (int r = 0; r < 4; ++r) {
                int gm = m0 + wm * 64 + mt * 16 + 4 * g + r;
                int gn = n0 + wn * 32 + nt * 16 + li;
                if (gn < N) {
                    float v = acc[mt][nt][r];
                    if (EPI == 1) v += add[(size_t)gm * N + gn];
                    C[(size_t)gm * N + gn] = v;
                }
            }
}

// ---------------- shared expert: gact = silu(x@wg)*(x@wu), bf16 out ----------------
__global__ __launch_bounds__(256)
void k_shexp(const short* __restrict__ X, const short* __restrict__ WGt, const short* __restrict__ WUt,
             short* __restrict__ gact) {
    __shared__ __align__(16) short As[128 * 64];
    __shared__ __align__(16) short Bg[64 * 64];
    __shared__ __align__(16) short Bu[64 * 64];
    int tid = threadIdx.x;
    int w = tid >> 6, l = tid & 63, g = l >> 4, li = l & 15;
    int wm = w >> 1, wn = w & 1;
    int m0 = blockIdx.x * 128, n0 = blockIdx.y * 64;
    f32x4 ag[4][2] = {}, au[4][2] = {};
    for (int k0 = 0; k0 < 512; k0 += 64) {
        __syncthreads();
#pragma unroll
        for (int p = 0; p < 4; ++p) {
            int flat = p * 256 + tid;
            int row = flat >> 3, ch = flat & 7;
            *(int4*)&As[row * 64 + ((ch ^ (row & 7)) * 8)] =
                *(const int4*)(X + (size_t)(m0 + row) * 512 + k0 + 8 * ch);
        }
#pragma unroll
        for (int p = 0; p < 2; ++p) {
            int flat = p * 256 + tid;
            int n = flat >> 3, ch = flat & 7;
            *(int4*)&Bg[n * 64 + ((ch ^ (n & 7)) * 8)] = *(const int4*)(WGt + (size_t)(n0 + n) * 512 + k0 + 8 * ch);
            *(int4*)&Bu[n * 64 + ((ch ^ (n & 7)) * 8)] = *(const int4*)(WUt + (size_t)(n0 + n) * 512 + k0 + 8 * ch);
        }
        __syncthreads();
#pragma unroll
        for (int kc = 0; kc < 2; ++kc) {
            s16x8 af[4], bg[2], bu[2];
#pragma unroll
            for (int mt = 0; mt < 4; ++mt) {
                int row = wm * 64 + mt * 16 + li;
                af[mt] = *(const s16x8*)&As[row * 64 + (((4 * kc + g) ^ (li & 7)) * 8)];
            }
#pragma unroll
            for (int nt = 0; nt < 2; ++nt) {
                int n = wn * 32 + nt * 16 + li;
                bg[nt] = *(const s16x8*)&Bg[n * 64 + (((4 * kc + g) ^ (li & 7)) * 8)];
                bu[nt] = *(const s16x8*)&Bu[n * 64 + (((4 * kc + g) ^ (li & 7)) * 8)];
            }
#pragma unroll
            for (int mt = 0; mt < 4; ++mt)
#pragma unroll
                for (int nt = 0; nt < 2; ++nt) {
                    ag[mt][nt] = __builtin_amdgcn_mfma_f32_16x16x32_bf16(af[mt], bg[nt], ag[mt][nt], 0, 0, 0);
                    au[mt][nt] = __builtin_amdgcn_mfma_f32_16x16x32_bf16(af[mt], bu[nt], au[mt][nt], 0, 0, 0);
                }
        }
    }
#pragma unroll
    for (int mt = 0; mt < 4; ++mt)
#pragma unroll
        for (int nt = 0; nt < 2; ++nt)
#pragma unroll
            for (int r = 0; r < 4; ++r) {
                int gm = m0 + wm * 64 + mt * 16 + 4 * g + r;
                int gn = n0 + wn * 32 + nt * 16 + li;
                float gv = ag[mt][nt][r], uv = au[mt][nt][r];
                gact[(size_t)gm * 256 + gn] = f2b(gv / (1.f + __expf(-gv)) * uv);
            }
}

// ---------------- q build: split + RoPE -> bf16 ----------------
__global__ void k_build_q(const float* __restrict__ qcr, short* __restrict__ qb) {
    int gid = blockIdx.x * 256 + threadIdx.x;   // 16*2048*96
    int d = gid % 96;
    int rs = gid / 96;
    int srow = rs & 2047;
    int bh = rs >> 11;
    int b = bh >> 3, h = bh & 7;
    int t = b * 2048 + srow;
    const float* src = qcr + (size_t)t * 768 + h * 96;
    float val;
    if (d < 64) {
        val = src[d];
    } else {
        int d2 = d - 64;
        int fi = d2 & 15;
        float ang = (float)srow * __expf(-((float)(2 * fi) / 32.f) * 9.210340371976184f);
        float s, c; __sincosf(ang, &s, &c);
        float x = src[64 + d2];
        float r = (d2 < 16) ? -src[64 + d2 + 16] : src[64 + d2 - 16];
        val = x * c + r * s;
    }
    qb[gid] = f2b(val);
}

// ---------------- k build: split + RoPE(k_r broadcast) -> bf16 ----------------
__global__ void k_build_k(const float* __restrict__ kvb, const float* __restrict__ ckv,
                          short* __restrict__ kb) {
    int gid = blockIdx.x * 256 + threadIdx.x;   // 16*2048*96
    int d = gid % 96;
    int rs = gid / 96;
    int srow = rs & 2047;
    int bh = rs >> 11;
    int b = bh >> 3, h = bh & 7;
    int t = b * 2048 + srow;
    float val;
    if (d < 64) {
        val = kvb[(size_t)t * 1024 + h * 128 + d];
    } else {
        int d2 = d - 64;
        int fi = d2 & 15;
        float ang = (float)srow * __expf(-((float)(2 * fi) / 32.f) * 9.210340371976184f);
        float s, c; __sincosf(ang, &s, &c);
        float x = ckv[(size_t)t * 160 + 128 + d2];
        float r = (d2 < 16) ? -ckv[(size_t)t * 160 + 128 + d2 + 16]
                            :  ckv[(size_t)t * 160 + 128 + d2 - 16];
        val = x * c + r * s;
    }
    kb[gid] = f2b(val);
}

// ---------------- v build transposed: vbt[bh][dim64][key2048] bf16 ----------------
__global__ void k_build_vt(const float* __restrict__ kvb, short* __restrict__ vbt) {
    int gid = blockIdx.x * 256 + threadIdx.x;   // 16*64*2048
    int key = gid & 2047;
    int dim = (gid >> 11) & 63;
    int bh = gid >> 17;
    int b = bh >> 3, h = bh & 7;
    vbt[gid] = f2b(kvb[(size_t)(b * 2048 + key) * 1024 + h * 128 + 64 + dim]);
}

// ---------------- MFMA flash attention: 4 waves/block, wave = 16 q cols ----------------
__global__ __launch_bounds__(256)
void k_attn(const short* __restrict__ qb, const short* __restrict__ kb,
            const short* __restrict__ vbt, short* __restrict__ ao) {
    __shared__ __align__(16) short Ks[64 * 96];
    __shared__ __align__(16) short Vs[64 * 64];
    int tid = threadIdx.x;
    int w = tid >> 6, l = tid & 63, g = l >> 4, li = l & 15;
    int bh = blockIdx.x >> 5, qt = blockIdx.x & 31;
    int b = bh >> 3, h = bh & 7;
    int qcol = qt * 64 + w * 16 + li;
    const float scale = 0.10206207261596575f;  // 1/sqrt(96)

    s16x8 qf[3];
    const short* qp = qb + (size_t)(bh * 2048 + qcol) * 96;
#pragma unroll
    for (int c = 0; c < 3; ++c) qf[c] = *(const s16x8*)(qp + 32 * c + 8 * g);

    f32x4 o[4] = {};
    float m = -INFINITY, lsum = 0.f;
    const short* kbase = kb + (size_t)bh * 2048 * 96;
    const short* vbase = vbt + (size_t)bh * 64 * 2048;

    for (int k0 = 0; k0 < 2048; k0 += 64) {
        __syncthreads();
#pragma unroll
        for (int p = 0; p < 3; ++p) {
            int flat = p * 256 + tid;
            int key = flat / 12, u = flat % 12;
            *(int4*)&Ks[key * 96 + 8 * u] = *(const int4*)(kbase + (size_t)(k0 + key) * 96 + 8 * u);
        }
#pragma unroll
        for (int p = 0; p < 2; ++p) {
            int flat = p * 256 + tid;
            int dim = flat >> 3, kc8 = flat & 7;
            int4 v = *(const int4*)(vbase + (size_t)dim * 2048 + k0 + 8 * kc8);
            int sw = dim & 15;
            *(int2*)&Vs[dim * 64 + (((2 * kc8) ^ sw) * 4)]     = make_int2(v.x, v.y);
            *(int2*)&Vs[dim * 64 + (((2 * kc8 + 1) ^ sw) * 4)] = make_int2(v.z, v.w);
        }
        __syncthreads();

        // S^T[key][q] = K · Q^T
        f32x4 s[4];
#pragma unroll
        for (int kt = 0; kt < 4; ++kt) {
            f32x4 acc = {};
#pragma unroll
            for (int c = 0; c < 3; ++c) {
                s16x8 kf = *(const s16x8*)&Ks[(kt * 16 + li) * 96 + 32 * c + 8 * g];
                acc = __builtin_amdgcn_mfma_f32_16x16x32_bf16(kf, qf[c], acc, 0, 0, 0);
            }
#pragma unroll
            for (int r = 0; r < 4; ++r) acc[r] *= scale;
            s[kt] = acc;
        }
        // per-q max over 64 keys
        float pm = -INFINITY;
#pragma unroll
        for (int kt = 0; kt < 4; ++kt)
#pragma unroll
            for (int r = 0; r < 4; ++r) pm = fmaxf(pm, s[kt][r]);
        pm = fmaxf(pm, __shfl_xor(pm, 16));
        pm = fmaxf(pm, __shfl_xor(pm, 32));
        float mn = fmaxf(m, pm);
        float corr = __expf(m - mn);
        float ps = 0.f;
#pragma unroll
        for (int kt = 0; kt < 4; ++kt)
#pragma unroll
            for (int r = 0; r < 4; ++r) { float p = __expf(s[kt][r] - mn); s[kt][r] = p; ps += p; }
        ps += __shfl_xor(ps, 16);
        ps += __shfl_xor(ps, 32);
        lsum = lsum * corr + ps;
        m = mn;
#pragma unroll
        for (int dt = 0; dt < 4; ++dt)
#pragma unroll
            for (int r = 0; r < 4; ++r) o[dt][r] *= corr;

        // P^T fragments (lane-local)
        s16x8 pf[2];
#pragma unroll
        for (int kc = 0; kc < 2; ++kc) {
            s16x8 t;
#pragma unroll
            for (int r = 0; r < 4; ++r) { t[r] = f2b(s[2 * kc][r]); t[4 + r] = f2b(s[2 * kc + 1][r]); }
            pf[kc] = t;
        }
        // O^T += V^T · P^T
#pragma unroll
        for (int dt = 0; dt < 4; ++dt) {
            int dim = dt * 16 + li;
#pragma unroll
            for (int kc = 0; kc < 2; ++kc) {
                int2 a0 = *(const int2*)&Vs[dim * 64 + (((8 * kc + g) ^ li) * 4)];
                int2 a1 = *(const int2*)&Vs[dim * 64 + (((8 * kc + 4 + g) ^ li) * 4)];
                union { s16x8 v; int i[4]; } vf;
                vf.i[0] = a0.x; vf.i[1] = a0.y; vf.i[2] = a1.x; vf.i[3] = a1.y;
                o[dt] = __builtin_amdgcn_mfma_f32_16x16x32_bf16(vf.v, pf[kc], o[dt], 0, 0, 0);
            }
        }
    }
    float inv = 1.f / lsum;
    short* op = ao + (size_t)(b * 2048 + qcol) * 512 + h * 64;
#pragma unroll
    for (int dt = 0; dt < 4; ++dt)
#pragma unroll
        for (int r = 0; r < 4; ++r)
            op[dt * 16 + 4 * g + r] = f2b(o[dt][r] * inv);
}

// ---------------- router: wave-parallel scoring + top-4, NO atomics ----------------
__global__ __launch_bounds__(256)
void k_router(const float* __restrict__ xn2, const float* __restrict__ wg,
              int4* __restrict__ toke, float4* __restrict__ tokw) {
    int wid = threadIdx.x >> 6, lane = threadIdx.x & 63;
    int t = blockIdx.x * 4 + wid;
    int e = lane & 15, chunk = lane >> 4;          // 16 experts x 4 k-chunks
    const float* xp = xn2 + (size_t)t * 512 + chunk * 128;
    const float* wp = wg + (size_t)chunk * 128 * 16 + e;
    float s = 0.f;
#pragma unroll 16
    for (int k = 0; k < 128; ++k) s = fmaf(xp[k], wp[(size_t)k * 16], s);
    s += __shfl_xor(s, 16);
    s += __shfl_xor(s, 32);
    float sc = 1.f / (1.f + expf(-s));             // all 4 replicas of expert e hold sc
    unsigned sel = 0;
    float tw[4]; int ti[4];
#pragma unroll
    for (int kk = 0; kk < 4; ++kk) {
        float cand = ((sel >> e) & 1u) ? -1e30f : sc;
        float mx = cand;
        mx = fmaxf(mx, __shfl_xor(mx, 1));
        mx = fmaxf(mx, __shfl_xor(mx, 2));
        mx = fmaxf(mx, __shfl_xor(mx, 4));
        mx = fmaxf(mx, __shfl_xor(mx, 8));
        unsigned long long msk = __ballot(cand == mx);
        int bi = (__ffsll(msk) - 1) & 15;          // lowest lane => lowest expert idx (tie-break matches top_k)
        tw[kk] = mx; ti[kk] = bi;
        sel |= 1u << bi;
    }
    if (lane == 0) {
        float inv = 1.f / (tw[0] + tw[1] + tw[2] + tw[3]);
        toke[t] = make_int4(ti[0], ti[1], ti[2], ti[3]);
        tokw[t] = make_float4(tw[0] * inv, tw[1] * inv, tw[2] * inv, tw[3] * inv);
    }
}

// ---------------- scatter: block-aggregated expert list build ----------------
// 16 blocks x 256 threads; thread = one token. LDS histogram -> 16 global atomics/block.
__global__ __launch_bounds__(256)
void k_scatter(const int4* __restrict__ toke, const float4* __restrict__ tokw,
               float* __restrict__ ewt, int* __restrict__ ecnt, int* __restrict__ etok) {
    __shared__ int lcnt[16];
    __shared__ int lbase[16];
    int tid = threadIdx.x;
    int t = blockIdx.x * 256 + tid;
    if (tid < 16) lcnt[tid] = 0;
    __syncthreads();
    int4 e4 = toke[t];
    float4 w4 = tokw[t];
    int es[4] = { e4.x, e4.y, e4.z, e4.w };
    float wv[4] = { w4.x, w4.y, w4.z, w4.w };
    int ls[4];
#pragma unroll
    for (int kk = 0; kk < 4; ++kk) ls[kk] = atomicAdd(&lcnt[es[kk]], 1);
    __syncthreads();
    if (tid < 16) lbase[tid] = atomicAdd(&ecnt[tid], lcnt[tid]);
    __syncthreads();
#pragma unroll
    for (int kk = 0; kk < 4; ++kk) {
        int slot = lbase[es[kk]] + ls[kk];
        etok[es[kk] * 4096 + slot] = t * 4 + kk;
        ewt[es[kk] * 4096 + slot] = wv[kk];
    }
}

// ---------------- MoE stage 1 (MFMA): eact = silu(x@wg)*(x@wu) ----------------
__global__ __launch_bounds__(256)
void k_moe1m(const short* __restrict__ X, const short* __restrict__ WGt, const short* __restrict__ WUt,
             const int* __restrict__ ecnt, const int* __restrict__ etok, short* __restrict__ eact) {
    int e = blockIdx.x >> 5, mt128 = blockIdx.x & 31;
    int cnt = ecnt[e];
    int base = mt128 * 128;
    if (base >= cnt) return;
    int rows = min(128, cnt - base);
    int n0 = blockIdx.y * 64;
    __shared__ __align__(16) short As[128 * 64];
    __shared__ __align__(16) short Bg[64 * 64];
    __shared__ __align__(16) short Bu[64 * 64];
    __shared__ int toks[128];
    int tid = threadIdx.x;
    if (tid < 128) toks[tid] = (tid < rows) ? etok[e * 4096 + base + tid] : -1;
    __syncthreads();
    int w = tid >> 6, l = tid & 63, g = l >> 4, li = l & 15;
    int wm = w >> 1, wn = w & 1;
    const short* wgp = WGt + (size_t)e * 256 * 512;
    const short* wup = WUt + (size_t)e * 256 * 512;
    f32x4 ag[4][2] = {}, au[4][2] = {};
    for (int k0 = 0; k0 < 512; k0 += 64) {
        __syncthreads();
#pragma unroll
        for (int p = 0; p < 4; ++p) {
            int flat = p * 256 + tid;
            int row = flat >> 3, ch = flat & 7;
            int tk = toks[row];
            int4 v = {0, 0, 0, 0};
            if (tk >= 0) v = *(const int4*)(X + (size_t)(tk >> 2) * 512 + k0 + 8 * ch);
            *(int4*)&As[row * 64 + ((ch ^ (row & 7)) * 8)] = v;
        }
#pragma unroll
        for (int p = 0; p < 2; ++p) {
            int flat = p * 256 + tid;
            int n = flat >> 3, ch = flat & 7;
            *(int4*)&Bg[n * 64 + ((ch ^ (n & 7)) * 8)] = *(const int4*)(wgp + (size_t)(n0 + n) * 512 + k0 + 8 * ch);
            *(int4*)&Bu[n * 64 + ((ch ^ (n & 7)) * 8)] = *(const int4*)(wup + (size_t)(n0 + n) * 512 + k0 + 8 * ch);
        }
        __syncthreads();
#pragma unroll
        for (int kc = 0; kc < 2; ++kc) {
            s16x8 af[4], bg[2], bu[2];
#pragma unroll
            for (int mt = 0; mt < 4; ++mt) {
                int row = wm * 64 + mt * 16 + li;
                af[mt] = *(const s16x8*)&As[row * 64 + (((4 * kc + g) ^ (li & 7)) * 8)];
            }
#pragma unroll
            for (int nt = 0; nt < 2; ++nt) {
                int n = wn * 32 + nt * 16 + li;
                bg[nt] = *(const s16x8*)&Bg[n * 64 + (((4 * kc + g) ^ (li & 7)) * 8)];
                bu[nt] = *(const s16x8*)&Bu[n * 64 + (((4 * kc + g) ^ (li & 7)) * 8)];
            }
#pragma unroll
            for (int mt = 0; mt < 4; ++mt)
#pragma unroll
                for (int nt = 0; nt < 2; ++nt) {
                    ag[mt][nt] = __builtin_amdgcn_mfma_f32_16x16x32_bf16(af[mt], bg[nt], ag[mt][nt], 0, 0, 0);
                    au[mt][nt] = __builtin_amdgcn_mfma_f32_16x16x32_bf16(af[mt], bu[nt], au[mt][nt], 0, 0, 0);
                }
        }
    }
#pragma unroll
    for (int mt = 0; mt < 4; ++mt)
#pragma unroll
        for (int nt = 0; nt < 2; ++nt)
#pragma unroll
            for (int r = 0; r < 4; ++r) {
                int local = wm * 64 + mt * 16 + 4 * g + r;
                if (local < rows) {
                    int entry = toks[local];
                    int gn = n0 + wn * 32 + nt * 16 + li;
                    float gv = ag[mt][nt][r], uv = au[mt][nt][r];
                    eact[(size_t)entry * 256 + gn] = f2b(gv / (1.f + __expf(-gv)) * uv);
                }
            }
}

// ---------------- MoE stage 2 (MFMA): out += w * (eact @ wd) ----------------
__global__ __launch_bounds__(256)
void k_moe2m(const short* __restrict__ EA, const short* __restrict__ WDt,
             const int* __restrict__ ecnt, const int* __restrict__ etok,
             const float* __restrict__ ewt, float* __restrict__ oacc) {
    int e = blockIdx.x >> 5, mt128 = blockIdx.x & 31;
    int cnt = ecnt[e];
    int base = mt128 * 128;
    if (base >= cnt) return;
    int rows = min(128, cnt - base);
    int n0 = blockIdx.y * 64;
    __shared__ __align__(16) short As[128 * 64];
    __shared__ __align__(16) short Bs[64 * 64];
    __shared__ int toks[128];
    __shared__ float wts[128];
    int tid = threadIdx.x;
    if (tid < 128) {
        toks[tid] = (tid < rows) ? etok[e * 4096 + base + tid] : -1;
        wts[tid]  = (tid < rows) ? ewt[e * 4096 + base + tid] : 0.f;
    }
    __syncthreads();
    int w = tid >> 6, l = tid & 63, g = l >> 4, li = l & 15;
    int wm = w >> 1, wn = w & 1;
    const short* wdp = WDt + (size_t)e * 512 * 256;
    f32x4 acc[4][2] = {};
    for (int k0 = 0; k0 < 256; k0 += 64) {
        __syncthreads();
#pragma unroll
        for (int p = 0; p < 4; ++p) {
            int flat = p * 256 + tid;
            int row = flat >> 3, ch = flat & 7;
            int tk = toks[row];
            int4 v = {0, 0, 0, 0};
            if (tk >= 0) v = *(const int4*)(EA + (size_t)tk * 256 + k0 + 8 * ch);
            *(int4*)&As[row * 64 + ((ch ^ (row & 7)) * 8)] = v;
        }
#pragma unroll
        for (int p = 0; p < 2; ++p) {
            int flat = p * 256 + tid;
            int n = flat >> 3, ch = flat & 7;
            *(int4*)&Bs[n * 64 + ((ch ^ (n & 7)) * 8)] = *(const int4*)(wdp + (size_t)(n0 + n) * 256 + k0 + 8 * ch);
        }
        __syncthreads();
#pragma unroll
        for (int kc = 0; kc < 2; ++kc) {
            s16x8 af[4], bf[2];
#pragma unroll
            for (int mt = 0; mt < 4; ++mt) {
                int row = wm * 64 + mt * 16 + li;
                af[mt] = *(const s16x8*)&As[row * 64 + (((4 * kc + g) ^ (li & 7)) * 8)];
            }
#pragma unroll
            for (int nt = 0; nt < 2; ++nt) {
                int n = wn * 32 + nt * 16 + li;
                bf[nt] = *(const s16x8*)&Bs[n * 64 + (((4 * kc + g) ^ (li & 7)) * 8)];
            }
#pragma unroll
            for (int mt = 0; mt < 4; ++mt)
#pragma unroll
                for (int nt = 0; nt < 2; ++nt)
                    acc[mt][nt] = __builtin_amdgcn_mfma_f32_16x16x32_bf16(af[mt], bf[nt], acc[mt][nt], 0, 0, 0);
        }
    }
#pragma unroll
    for (int mt = 0; mt < 4; ++mt)
#pragma unroll
        for (int nt = 0; nt < 2; ++nt)
#pragma unroll
            for (int r = 0; r < 4; ++r) {
                int local = wm * 64 + mt * 16 + 4 * g + r;
                if (local < rows) {
                    int tok = toks[local] >> 2;
                    int gn = n0 + wn * 32 + nt * 16 + li;
                    atomicAdd(&oacc[(size_t)tok * 512 + gn], acc[mt][nt][r] * wts[local]);
                }
            }
}

// ---------------- host launcher ----------------
extern "C" void kernel_launch(void* const* d_in, const int* in_sizes, int n_in,
                              void* d_out, int out_size, void* d_ws, size_t ws_size,
                              hipStream_t stream) {
    const float* hs       = (const float*)d_in[0];
    const float* w_innorm = (const float*)d_in[1];
    const float* w_dq     = (const float*)d_in[2];
    const float* w_qnorm  = (const float*)d_in[3];
    const float* w_uq     = (const float*)d_in[4];
    const float* w_dkv    = (const float*)d_in[5];
    const float* w_kvnorm = (const float*)d_in[6];
    const float* w_ukv    = (const float*)d_in[7];
    const float* w_o      = (const float*)d_in[8];
    const float* w_post   = (const float*)d_in[9];
    const float* w_gate   = (const float*)d_in[10];
    const float* sh_wg    = (const float*)d_in[11];
    const float* sh_wu    = (const float*)d_in[12];
    const float* sh_wd    = (const float*)d_in[13];
    const float* r_wg     = (const float*)d_in[14];
    const float* r_wu     = (const float*)d_in[15];
    const float* r_wd     = (const float*)d_in[16];

    float* ws   = (float*)d_ws;
    float* cq   = ws + OFF_CQ;
    float* ckv  = ws + OFF_CKV;
    float* qcr  = ws + OFF_QCR;
    float* kvb  = ws + OFF_KVB;
    float* r2   = ws + OFF_R2;
    float* xn2  = ws + OFF_XN2;
    int4*  toke = (int4*)(ws + OFF_TOKE);
    float4* tokw = (float4*)(ws + OFF_TOKW);
    float* ewt  = ws + OFF_EWT;
    int*   ecnt = (int*)(ws + OFF_ECNT);
    int*   etok = (int*)(ws + OFF_ETOK);
    short* xnb   = (short*)(ws + OFF_XNB);
    short* cqnb  = (short*)(ws + OFF_CQNB);
    short* ckvnb = (short*)(ws + OFF_CKVNB);
    short* qb    = (short*)(ws + OFF_QB);
    short* kb    = (short*)(ws + OFF_KB);
    short* vbt   = (short*)(ws + OFF_VBT);
    short* aob   = (short*)(ws + OFF_AOB);
    short* xn2b  = (short*)(ws + OFF_XN2B);
    short* gact  = (short*)(ws + OFF_GACT);
    short* eact  = (short*)(ws + OFF_EACT);
    short* wdqT  = (short*)(ws + OFF_WDQT);
    short* wdkvT = (short*)(ws + OFF_WDKVT);
    short* wuqT  = (short*)(ws + OFF_WUQT);
    short* wukvT = (short*)(ws + OFF_WUKVT);
    short* woT   = (short*)(ws + OFF_WOT);
    short* shwgT = (short*)(ws + OFF_SHWGT);
    short* shwuT = (short*)(ws + OFF_SHWUT);
    short* shwdT = (short*)(ws + OFF_SHWDT);
    short* rwgT  = (short*)(ws + OFF_RWGT);
    short* rwuT  = (short*)(ws + OFF_RWUT);
    short* rwdT  = (short*)(ws + OFF_RWDT);

    float* outF = (float*)d_out;   // final accumulator lives directly in d_out

    // 0. weight convert+transpose (bf16 [N][K])
    k_cvt_t<<<dim3(8, 16, 1),  256, 0, stream>>>(w_dq,  wdqT,  512, 256);
    k_cvt_t<<<dim3(5, 16, 1),  256, 0, stream>>>(w_dkv, wdkvT, 512, 160);
    k_cvt_t<<<dim3(24, 8, 1),  256, 0, stream>>>(w_uq,  wuqT,  256, 768);
    k_cvt_t<<<dim3(32, 4, 1),  256, 0, stream>>>(w_ukv, wukvT, 128, 1024);
    k_cvt_t<<<dim3(16, 16, 1), 256, 0, stream>>>(w_o,   woT,   512, 512);
    k_cvt_t<<<dim3(8, 16, 1),  256, 0, stream>>>(sh_wg, shwgT, 512, 256);
    k_cvt_t<<<dim3(8, 16, 1),  256, 0, stream>>>(sh_wu, shwuT, 512, 256);
    k_cvt_t<<<dim3(16, 8, 1),  256, 0, stream>>>(sh_wd, shwdT, 256, 512);
    k_cvt_t<<<dim3(8, 16, 16), 256, 0, stream>>>(r_wg,  rwgT,  512, 256);
    k_cvt_t<<<dim3(8, 16, 16), 256, 0, stream>>>(r_wu,  rwuT,  512, 256);
    k_cvt_t<<<dim3(16, 8, 16), 256, 0, stream>>>(r_wd,  rwdT,  256, 512);

    // 1. input RMSNorm -> bf16
    k_rms<<<Tt, 256, 0, stream>>>(hs, 512, w_innorm, nullptr, xnb, 512, 512);
    // 2. down-projections
    k_mgemm<0><<<dim3(4, 32), 256, 0, stream>>>(xnb, wdqT, cq, nullptr, 256, 512);
    k_mgemm<0><<<dim3(3, 32), 256, 0, stream>>>(xnb, wdkvT, ckv, nullptr, 160, 512);
    // 3. latent norms -> bf16
    k_rms<<<Tt, 256, 0, stream>>>(cq, 256, w_qnorm, nullptr, cqnb, 256, 256);
    k_rms<<<Tt, 256, 0, stream>>>(ckv, 160, w_kvnorm, nullptr, ckvnb, 128, 128);
    // 4. up-projections
    k_mgemm<0><<<dim3(12, 32), 256, 0, stream>>>(cqnb, wuqT, qcr, nullptr, 768, 256);
    k_mgemm<0><<<dim3(16, 32), 256, 0, stream>>>(ckvnb, wukvT, kvb, nullptr, 1024, 128);
    // 5. build q/k/v (RoPE) -> bf16
    k_build_q<<<(16 * 2048 * 96) / 256, 256, 0, stream>>>(qcr, qb);
    k_build_k<<<(16 * 2048 * 96) / 256, 256, 0, stream>>>(kvb, ckv, kb);
    k_build_vt<<<(16 * 64 * 2048) / 256, 256, 0, stream>>>(kvb, vbt);
    // 6. MFMA flash attention
    k_attn<<<512, 256, 0, stream>>>(qb, kb, vbt, aob);
    // 7. output proj + residual
    k_mgemm<1><<<dim3(8, 32), 256, 0, stream>>>(aob, woT, r2, hs, 512, 512);
    // 8. post norm (f32 for router + bf16 for GEMMs)
    k_rms<<<Tt, 256, 0, stream>>>(r2, 512, w_post, xn2, xn2b, 512, 512);
    // 9. shared expert (fused dual-GEMM + swiglu) then down-proj + residual into d_out
    k_shexp<<<dim3(32, 4), 256, 0, stream>>>(xn2b, shwgT, shwuT, gact);
    k_mgemm<1><<<dim3(8, 32), 256, 0, stream>>>(gact, shwdT, outF, r2, 512, 256);
    // 10. router (no atomics) + block-aggregated scatter + MoE
    k_router<<<Tt / 4, 256, 0, stream>>>(xn2, w_gate, toke, tokw);
    hipMemsetAsync(ecnt, 0, NEn * sizeof(int), stream);
    k_scatter<<<16, 256, 0, stream>>>(toke, tokw, ewt, ecnt, etok);
    k_moe1m<<<dim3(512, 4), 256, 0, stream>>>(xn2b, rwgT, rwuT, ecnt, etok, eact);
    k_moe2m<<<dim3(512, 8), 256, 0, stream>>>(eact, rwdT, ecnt, etok, ewt, outF);
}

// Round 7
// 289.480 us; speedup vs baseline: 14.3615x; 1.2006x over previous
//
#include <hip/hip_runtime.h>
#include <hip/hip_bf16.h>
#include <math.h>

typedef float f32x4 __attribute__((ext_vector_type(4)));
typedef short s16x8 __attribute__((ext_vector_type(8)));

// ---------------- problem constants ----------------
constexpr int Tt = 4096;
constexpr int NEn = 16;
constexpr float EPSf = 1.1920929e-07f;

__device__ __forceinline__ short f2b(float f) {
    union { __hip_bfloat16 h; short s; } u;
    u.h = __float2bfloat16(f);
    return u.s;
}

// ---------------- workspace layout (float elements, 16-float aligned) ----------------
constexpr size_t alg(size_t x) { return (x + 15) & ~(size_t)15; }
// f32 buffers
constexpr size_t OFF_CQ   = 0;                                   // T*256 f32
constexpr size_t OFF_CKV  = alg(OFF_CQ   + (size_t)Tt * 256);    // T*160 f32
constexpr size_t OFF_QCR  = alg(OFF_CKV  + (size_t)Tt * 160);    // T*768 f32
constexpr size_t OFF_KVB  = alg(OFF_QCR  + (size_t)Tt * 768);    // T*1024 f32
constexpr size_t OFF_R2   = alg(OFF_KVB  + (size_t)Tt * 1024);   // T*512 f32
constexpr size_t OFF_XN2  = alg(OFF_R2   + (size_t)Tt * 512);    // T*512 f32
constexpr size_t OFF_TOKE = alg(OFF_XN2  + (size_t)Tt * 512);    // T*4 ints (top-4 experts)
constexpr size_t OFF_TOKW = alg(OFF_TOKE + (size_t)Tt * 4);      // T*4 f32 (top-4 weights)
constexpr size_t OFF_EWT  = alg(OFF_TOKW + (size_t)Tt * 4);      // 16*4096 f32
constexpr size_t OFF_ECNT = alg(OFF_EWT  + (size_t)NEn * Tt);    // ints
constexpr size_t OFF_ETOK = alg(OFF_ECNT + 64);                  // 16*4096 ints
constexpr size_t OFF_WL   = alg(OFF_ETOK + (size_t)NEn * Tt);    // 160 ints (worklist, max 144)
constexpr size_t OFF_WCNT = alg(OFF_WL   + 160);                 // 1 int
// bf16 buffers (element counts halved into float units)
constexpr size_t OFF_XNB   = alg(OFF_WCNT + 16);                     // T*512 bf16
constexpr size_t OFF_CQNB  = alg(OFF_XNB   + (size_t)Tt * 512 / 2);  // T*256 bf16
constexpr size_t OFF_CKVNB = alg(OFF_CQNB  + (size_t)Tt * 256 / 2);  // T*128 bf16
constexpr size_t OFF_QB    = alg(OFF_CKVNB + (size_t)Tt * 128 / 2);  // 16*2048*96 bf16
constexpr size_t OFF_KB    = alg(OFF_QB    + (size_t)16 * 2048 * 96 / 2);
constexpr size_t OFF_VBT   = alg(OFF_KB    + (size_t)16 * 2048 * 96 / 2); // 16*64*2048 bf16
constexpr size_t OFF_AOB   = alg(OFF_VBT   + (size_t)16 * 64 * 2048 / 2); // T*512 bf16
constexpr size_t OFF_XN2B  = alg(OFF_AOB   + (size_t)Tt * 512 / 2);
constexpr size_t OFF_GACT  = alg(OFF_XN2B  + (size_t)Tt * 512 / 2);  // T*256 bf16
constexpr size_t OFF_EACT  = alg(OFF_GACT  + (size_t)Tt * 256 / 2);  // 16384*256 bf16
// transposed bf16 weights [N][K]
constexpr size_t OFF_WDQT  = alg(OFF_EACT  + (size_t)16384 * 256 / 2);
constexpr size_t OFF_WDKVT = alg(OFF_WDQT  + (size_t)256 * 512 / 2);
constexpr size_t OFF_WUQT  = alg(OFF_WDKVT + (size_t)160 * 512 / 2);
constexpr size_t OFF_WUKVT = alg(OFF_WUQT  + (size_t)768 * 256 / 2);
constexpr size_t OFF_WOT   = alg(OFF_WUKVT + (size_t)1024 * 128 / 2);
constexpr size_t OFF_SHWGT = alg(OFF_WOT   + (size_t)512 * 512 / 2);
constexpr size_t OFF_SHWUT = alg(OFF_SHWGT + (size_t)256 * 512 / 2);
constexpr size_t OFF_SHWDT = alg(OFF_SHWUT + (size_t)256 * 512 / 2);
constexpr size_t OFF_RWGT  = alg(OFF_SHWDT + (size_t)512 * 256 / 2);
constexpr size_t OFF_RWUT  = alg(OFF_RWGT  + (size_t)16 * 256 * 512 / 2);
constexpr size_t OFF_RWDT  = alg(OFF_RWUT  + (size_t)16 * 256 * 512 / 2);

// ---------------- convert + transpose: src f32 [E][K][N] -> dst bf16 [E][N][K] ----------------
__global__ void k_cvt_t(const float* __restrict__ src, short* __restrict__ dst, int K, int N) {
    __shared__ float t[32][33];
    int n0 = blockIdx.x * 32, k0 = blockIdx.y * 32;
    size_t eo = (size_t)blockIdx.z * K * N;
    int c = threadIdx.x & 31, r = threadIdx.x >> 5;
#pragma unroll
    for (int i = 0; i < 4; ++i)
        t[r + 8 * i][c] = src[eo + (size_t)(k0 + r + 8 * i) * N + n0 + c];
    __syncthreads();
#pragma unroll
    for (int i = 0; i < 4; ++i)
        dst[eo + (size_t)(n0 + r + 8 * i) * K + k0 + c] = f2b(t[c][r + 8 * i]);
}

// ---------------- RMSNorm f32 in -> bf16 out (+ optional f32 out) ----------------
__global__ void k_rms(const float* __restrict__ in, int inStride, const float* __restrict__ w,
                      float* __restrict__ outF, short* __restrict__ outB, int outStride, int D) {
    int row = blockIdx.x, tid = threadIdx.x;
    __shared__ float xs[512];
    __shared__ float red[256];
    const float* ip = in + (size_t)row * inStride;
    float ss = 0.f;
    for (int i = tid; i < D; i += 256) { float v = ip[i]; xs[i] = v; ss += v * v; }
    red[tid] = ss; __syncthreads();
    for (int s = 128; s > 0; s >>= 1) { if (tid < s) red[tid] += red[tid + s]; __syncthreads(); }
    float sc = rsqrtf(red[0] / (float)D + EPSf);
    for (int i = tid; i < D; i += 256) {
        float v = xs[i] * sc * w[i];
        outB[(size_t)row * outStride + i] = f2b(v);
        if (outF) outF[(size_t)row * outStride + i] = v;
    }
}

// ---------------- MFMA GEMM (64x64 tile, 4 waves): C = A_b @ BT^T [+ add] ----------------
template <int EPI>  // 0: plain, 1: + f32 residual
__global__ __launch_bounds__(256)
void k_mgemm(const short* __restrict__ A, const short* __restrict__ BT,
             float* __restrict__ C, const float* __restrict__ add, int N, int K) {
    __shared__ __align__(16) short As[64 * 64];
    __shared__ __align__(16) short Bs[64 * 64];
    int tid = threadIdx.x;
    int w = tid >> 6, l = tid & 63, g = l >> 4, li = l & 15;
    int wm = w >> 1, wn = w & 1;
    int m0 = blockIdx.y * 64, n0 = blockIdx.x * 64;
    f32x4 acc[2][2] = {};
    for (int k0 = 0; k0 < K; k0 += 64) {
        __syncthreads();
#pragma unroll
        for (int p = 0; p < 2; ++p) {
            int flat = p * 256 + tid;
            int row = flat >> 3, ch = flat & 7;
            *(int4*)&As[row * 64 + ((ch ^ (row & 7)) * 8)] =
                *(const int4*)(A + (size_t)(m0 + row) * K + k0 + 8 * ch);
        }
#pragma unroll
        for (int p = 0; p < 2; ++p) {
            int flat = p * 256 + tid;
            int n = flat >> 3, ch = flat & 7;
            int4 v = {0, 0, 0, 0};
            if (n0 + n < N) v = *(const int4*)(BT + (size_t)(n0 + n) * K + k0 + 8 * ch);
            *(int4*)&Bs[n * 64 + ((ch ^ (n & 7)) * 8)] = v;
        }
        __syncthreads();
#pragma unroll
        for (int kc = 0; kc < 2; ++kc) {
            s16x8 af[2], bf[2];
#pragma unroll
            for (int mt = 0; mt < 2; ++mt) {
                int row = wm * 32 + mt * 16 + li;
                af[mt] = *(const s16x8*)&As[row * 64 + (((4 * kc + g) ^ (li & 7)) * 8)];
            }
#pragma unroll
            for (int nt = 0; nt < 2; ++nt) {
                int n = wn * 32 + nt * 16 + li;
                bf[nt] = *(const s16x8*)&Bs[n * 64 + (((4 * kc + g) ^ (li & 7)) * 8)];
            }
#pragma unroll
            for (int mt = 0; mt < 2; ++mt)
#pragma unroll
                for (int nt = 0; nt < 2; ++nt)
                    acc[mt][nt] = __builtin_amdgcn_mfma_f32_16x16x32_bf16(af[mt], bf[nt], acc[mt][nt], 0, 0, 0);
        }
    }
#pragma unroll
    for (int mt = 0; mt < 2; ++mt)
#pragma unroll
        for (int nt = 0; nt < 2; ++nt)
#pragma unroll
            for (int r = 0; r < 4; ++r) {
                int gm = m0 + wm * 32 + mt * 16 + 4 * g + r;
                int gn = n0 + wn * 32 + nt * 16 + li;
                if (gn < N) {
                    float v = acc[mt][nt][r];
                    if (EPI == 1) v += add[(size_t)gm * N + gn];
                    C[(size_t)gm * N + gn] = v;
                }
            }
}

// ---------------- shared expert (64x64 tile): gact = silu(x@wg)*(x@wu), bf16 out ----------------
__global__ __launch_bounds__(256)
void k_shexp(const short* __restrict__ X, const short* __restrict__ WGt, const short* __restrict__ WUt,
             short* __restrict__ gact) {
    __shared__ __align__(16) short As[64 * 64];
    __shared__ __align__(16) short Bg[64 * 64];
    __shared__ __align__(16) short Bu[64 * 64];
    int tid = threadIdx.x;
    int w = tid >> 6, l = tid & 63, g = l >> 4, li = l & 15;
    int wm = w >> 1, wn = w & 1;
    int m0 = blockIdx.x * 64, n0 = blockIdx.y * 64;
    f32x4 ag[2][2] = {}, au[2][2] = {};
    for (int k0 = 0; k0 < 512; k0 += 64) {
        __syncthreads();
#pragma unroll
        for (int p = 0; p < 2; ++p) {
            int flat = p * 256 + tid;
            int row = flat >> 3, ch = flat & 7;
            *(int4*)&As[row * 64 + ((ch ^ (row & 7)) * 8)] =
                *(const int4*)(X + (size_t)(m0 + row) * 512 + k0 + 8 * ch);
        }
        // both Bg and Bu staged in each p-iter: 2 iters x 256 thr = 512 int4 per array
#pragma unroll
        for (int p = 0; p < 2; ++p) {
            int flat = p * 256 + tid;
            int n = flat >> 3, ch = flat & 7;
            *(int4*)&Bg[n * 64 + ((ch ^ (n & 7)) * 8)] = *(const int4*)(WGt + (size_t)(n0 + n) * 512 + k0 + 8 * ch);
            *(int4*)&Bu[n * 64 + ((ch ^ (n & 7)) * 8)] = *(const int4*)(WUt + (size_t)(n0 + n) * 512 + k0 + 8 * ch);
        }
        __syncthreads();
#pragma unroll
        for (int kc = 0; kc < 2; ++kc) {
            s16x8 af[2], bg[2], bu[2];
#pragma unroll
            for (int mt = 0; mt < 2; ++mt) {
                int row = wm * 32 + mt * 16 + li;
                af[mt] = *(const s16x8*)&As[row * 64 + (((4 * kc + g) ^ (li & 7)) * 8)];
            }
#pragma unroll
            for (int nt = 0; nt < 2; ++nt) {
                int n = wn * 32 + nt * 16 + li;
                bg[nt] = *(const s16x8*)&Bg[n * 64 + (((4 * kc + g) ^ (li & 7)) * 8)];
                bu[nt] = *(const s16x8*)&Bu[n * 64 + (((4 * kc + g) ^ (li & 7)) * 8)];
            }
#pragma unroll
            for (int mt = 0; mt < 2; ++mt)
#pragma unroll
                for (int nt = 0; nt < 2; ++nt) {
                    ag[mt][nt] = __builtin_amdgcn_mfma_f32_16x16x32_bf16(af[mt], bg[nt], ag[mt][nt], 0, 0, 0);
                    au[mt][nt] = __builtin_amdgcn_mfma_f32_16x16x32_bf16(af[mt], bu[nt], au[mt][nt], 0, 0, 0);
                }
        }
    }
#pragma unroll
    for (int mt = 0; mt < 2; ++mt)
#pragma unroll
        for (int nt = 0; nt < 2; ++nt)
#pragma unroll
            for (int r = 0; r < 4; ++r) {
                int gm = m0 + wm * 32 + mt * 16 + 4 * g + r;
                int gn = n0 + wn * 32 + nt * 16 + li;
                float gv = ag[mt][nt][r], uv = au[mt][nt][r];
                gact[(size_t)gm * 256 + gn] = f2b(gv / (1.f + __expf(-gv)) * uv);
            }
}

// ---------------- q build: split + RoPE -> bf16 ----------------
__global__ void k_build_q(const float* __restrict__ qcr, short* __restrict__ qb) {
    int gid = blockIdx.x * 256 + threadIdx.x;   // 16*2048*96
    int d = gid % 96;
    int rs = gid / 96;
    int srow = rs & 2047;
    int bh = rs >> 11;
    int b = bh >> 3, h = bh & 7;
    int t = b * 2048 + srow;
    const float* src = qcr + (size_t)t * 768 + h * 96;
    float val;
    if (d < 64) {
        val = src[d];
    } else {
        int d2 = d - 64;
        int fi = d2 & 15;
        float ang = (float)srow * __expf(-((float)(2 * fi) / 32.f) * 9.210340371976184f);
        float s, c; __sincosf(ang, &s, &c);
        float x = src[64 + d2];
        float r = (d2 < 16) ? -src[64 + d2 + 16] : src[64 + d2 - 16];
        val = x * c + r * s;
    }
    qb[gid] = f2b(val);
}

// ---------------- k build: split + RoPE(k_r broadcast) -> bf16 ----------------
__global__ void k_build_k(const float* __restrict__ kvb, const float* __restrict__ ckv,
                          short* __restrict__ kb) {
    int gid = blockIdx.x * 256 + threadIdx.x;   // 16*2048*96
    int d = gid % 96;
    int rs = gid / 96;
    int srow = rs & 2047;
    int bh = rs >> 11;
    int b = bh >> 3, h = bh & 7;
    int t = b * 2048 + srow;
    float val;
    if (d < 64) {
        val = kvb[(size_t)t * 1024 + h * 128 + d];
    } else {
        int d2 = d - 64;
        int fi = d2 & 15;
        float ang = (float)srow * __expf(-((float)(2 * fi) / 32.f) * 9.210340371976184f);
        float s, c; __sincosf(ang, &s, &c);
        float x = ckv[(size_t)t * 160 + 128 + d2];
        float r = (d2 < 16) ? -ckv[(size_t)t * 160 + 128 + d2 + 16]
                            :  ckv[(size_t)t * 160 + 128 + d2 - 16];
        val = x * c + r * s;
    }
    kb[gid] = f2b(val);
}

// ---------------- v build transposed: vbt[bh][dim64][key2048] bf16 ----------------
__global__ void k_build_vt(const float* __restrict__ kvb, short* __restrict__ vbt) {
    int gid = blockIdx.x * 256 + threadIdx.x;   // 16*64*2048
    int key = gid & 2047;
    int dim = (gid >> 11) & 63;
    int bh = gid >> 17;
    int b = bh >> 3, h = bh & 7;
    vbt[gid] = f2b(kvb[(size_t)(b * 2048 + key) * 1024 + h * 128 + 64 + dim]);
}

// ---------------- MFMA flash attention: 4 waves/block, wave = 16 q cols ----------------
__global__ __launch_bounds__(256)
void k_attn(const short* __restrict__ qb, const short* __restrict__ kb,
            const short* __restrict__ vbt, short* __restrict__ ao) {
    __shared__ __align__(16) short Ks[64 * 96];
    __shared__ __align__(16) short Vs[64 * 64];
    int tid = threadIdx.x;
    int w = tid >> 6, l = tid & 63, g = l >> 4, li = l & 15;
    int bh = blockIdx.x >> 5, qt = blockIdx.x & 31;
    int b = bh >> 3, h = bh & 7;
    int qcol = qt * 64 + w * 16 + li;
    const float scale = 0.10206207261596575f;  // 1/sqrt(96)

    s16x8 qf[3];
    const short* qp = qb + (size_t)(bh * 2048 + qcol) * 96;
#pragma unroll
    for (int c = 0; c < 3; ++c) qf[c] = *(const s16x8*)(qp + 32 * c + 8 * g);

    f32x4 o[4] = {};
    float m = -INFINITY, lsum = 0.f;
    const short* kbase = kb + (size_t)bh * 2048 * 96;
    const short* vbase = vbt + (size_t)bh * 64 * 2048;

    for (int k0 = 0; k0 < 2048; k0 += 64) {
        __syncthreads();
#pragma unroll
        for (int p = 0; p < 3; ++p) {
            int flat = p * 256 + tid;
            int key = flat / 12, u = flat % 12;
            *(int4*)&Ks[key * 96 + 8 * u] = *(const int4*)(kbase + (size_t)(k0 + key) * 96 + 8 * u);
        }
#pragma unroll
        for (int p = 0; p < 2; ++p) {
            int flat = p * 256 + tid;
            int dim = flat >> 3, kc8 = flat & 7;
            int4 v = *(const int4*)(vbase + (size_t)dim * 2048 + k0 + 8 * kc8);
            int sw = dim & 15;
            *(int2*)&Vs[dim * 64 + (((2 * kc8) ^ sw) * 4)]     = make_int2(v.x, v.y);
            *(int2*)&Vs[dim * 64 + (((2 * kc8 + 1) ^ sw) * 4)] = make_int2(v.z, v.w);
        }
        __syncthreads();

        // S^T[key][q] = K · Q^T
        f32x4 s[4];
#pragma unroll
        for (int kt = 0; kt < 4; ++kt) {
            f32x4 acc = {};
#pragma unroll
            for (int c = 0; c < 3; ++c) {
                s16x8 kf = *(const s16x8*)&Ks[(kt * 16 + li) * 96 + 32 * c + 8 * g];
                acc = __builtin_amdgcn_mfma_f32_16x16x32_bf16(kf, qf[c], acc, 0, 0, 0);
            }
#pragma unroll
            for (int r = 0; r < 4; ++r) acc[r] *= scale;
            s[kt] = acc;
        }
        // per-q max over 64 keys
        float pm = -INFINITY;
#pragma unroll
        for (int kt = 0; kt < 4; ++kt)
#pragma unroll
            for (int r = 0; r < 4; ++r) pm = fmaxf(pm, s[kt][r]);
        pm = fmaxf(pm, __shfl_xor(pm, 16));
        pm = fmaxf(pm, __shfl_xor(pm, 32));
        float mn = fmaxf(m, pm);
        float corr = __expf(m - mn);
        float ps = 0.f;
#pragma unroll
        for (int kt = 0; kt < 4; ++kt)
#pragma unroll
            for (int r = 0; r < 4; ++r) { float p = __expf(s[kt][r] - mn); s[kt][r] = p; ps += p; }
        ps += __shfl_xor(ps, 16);
        ps += __shfl_xor(ps, 32);
        lsum = lsum * corr + ps;
        m = mn;
#pragma unroll
        for (int dt = 0; dt < 4; ++dt)
#pragma unroll
            for (int r = 0; r < 4; ++r) o[dt][r] *= corr;

        // P^T fragments (lane-local)
        s16x8 pf[2];
#pragma unroll
        for (int kc = 0; kc < 2; ++kc) {
            s16x8 t;
#pragma unroll
            for (int r = 0; r < 4; ++r) { t[r] = f2b(s[2 * kc][r]); t[4 + r] = f2b(s[2 * kc + 1][r]); }
            pf[kc] = t;
        }
        // O^T += V^T · P^T
#pragma unroll
        for (int dt = 0; dt < 4; ++dt) {
            int dim = dt * 16 + li;
#pragma unroll
            for (int kc = 0; kc < 2; ++kc) {
                int2 a0 = *(const int2*)&Vs[dim * 64 + (((8 * kc + g) ^ li) * 4)];
                int2 a1 = *(const int2*)&Vs[dim * 64 + (((8 * kc + 4 + g) ^ li) * 4)];
                union { s16x8 v; int i[4]; } vf;
                vf.i[0] = a0.x; vf.i[1] = a0.y; vf.i[2] = a1.x; vf.i[3] = a1.y;
                o[dt] = __builtin_amdgcn_mfma_f32_16x16x32_bf16(vf.v, pf[kc], o[dt], 0, 0, 0);
            }
        }
    }
    float inv = 1.f / lsum;
    short* op = ao + (size_t)(b * 2048 + qcol) * 512 + h * 64;
#pragma unroll
    for (int dt = 0; dt < 4; ++dt)
#pragma unroll
        for (int r = 0; r < 4; ++r)
            op[dt * 16 + 4 * g + r] = f2b(o[dt][r] * inv);
}

// ---------------- router: wave-parallel scoring + top-4, NO atomics ----------------
__global__ __launch_bounds__(256)
void k_router(const float* __restrict__ xn2, const float* __restrict__ wg,
              int4* __restrict__ toke, float4* __restrict__ tokw) {
    int wid = threadIdx.x >> 6, lane = threadIdx.x & 63;
    int t = blockIdx.x * 4 + wid;
    int e = lane & 15, chunk = lane >> 4;          // 16 experts x 4 k-chunks
    const float* xp = xn2 + (size_t)t * 512 + chunk * 128;
    const float* wp = wg + (size_t)chunk * 128 * 16 + e;
    float s = 0.f;
#pragma unroll 16
    for (int k = 0; k < 128; ++k) s = fmaf(xp[k], wp[(size_t)k * 16], s);
    s += __shfl_xor(s, 16);
    s += __shfl_xor(s, 32);
    float sc = 1.f / (1.f + expf(-s));             // all 4 replicas of expert e hold sc
    unsigned sel = 0;
    float tw[4]; int ti[4];
#pragma unroll
    for (int kk = 0; kk < 4; ++kk) {
        float cand = ((sel >> e) & 1u) ? -1e30f : sc;
        float mx = cand;
        mx = fmaxf(mx, __shfl_xor(mx, 1));
        mx = fmaxf(mx, __shfl_xor(mx, 2));
        mx = fmaxf(mx, __shfl_xor(mx, 4));
        mx = fmaxf(mx, __shfl_xor(mx, 8));
        unsigned long long msk = __ballot(cand == mx);
        int bi = (__ffsll(msk) - 1) & 15;          // lowest lane => lowest expert idx (tie-break matches top_k)
        tw[kk] = mx; ti[kk] = bi;
        sel |= 1u << bi;
    }
    if (lane == 0) {
        float inv = 1.f / (tw[0] + tw[1] + tw[2] + tw[3]);
        toke[t] = make_int4(ti[0], ti[1], ti[2], ti[3]);
        tokw[t] = make_float4(tw[0] * inv, tw[1] * inv, tw[2] * inv, tw[3] * inv);
    }
}

// ---------------- scatter: block-aggregated expert list build ----------------
__global__ __launch_bounds__(256)
void k_scatter(const int4* __restrict__ toke, const float4* __restrict__ tokw,
               float* __restrict__ ewt, int* __restrict__ ecnt, int* __restrict__ etok) {
    __shared__ int lcnt[16];
    __shared__ int lbase[16];
    int tid = threadIdx.x;
    int t = blockIdx.x * 256 + tid;
    if (tid < 16) lcnt[tid] = 0;
    __syncthreads();
    int4 e4 = toke[t];
    float4 w4 = tokw[t];
    int es[4] = { e4.x, e4.y, e4.z, e4.w };
    float wv[4] = { w4.x, w4.y, w4.z, w4.w };
    int ls[4];
#pragma unroll
    for (int kk = 0; kk < 4; ++kk) ls[kk] = atomicAdd(&lcnt[es[kk]], 1);
    __syncthreads();
    if (tid < 16) lbase[tid] = atomicAdd(&ecnt[tid], lcnt[tid]);
    __syncthreads();
#pragma unroll
    for (int kk = 0; kk < 4; ++kk) {
        int slot = lbase[es[kk]] + ls[kk];
        etok[es[kk] * 4096 + slot] = t * 4 + kk;
        ewt[es[kk] * 4096 + slot] = wv[kk];
    }
}

// ---------------- worklist: ecnt -> compact (expert, rowbase) tile list, TM=128 ----------------
__global__ void k_worklist(const int* __restrict__ ecnt, int* __restrict__ wl, int* __restrict__ wcnt) {
    if (threadIdx.x == 0 && blockIdx.x == 0) {
        int c = 0;
        for (int e = 0; e < 16; ++e) {
            int n = (ecnt[e] + 127) >> 7;
            for (int i = 0; i < n; ++i) wl[c++] = (e << 20) | (i << 7);
        }
        wcnt[0] = c;
    }
}

// ---------------- MoE stage 1 (MFMA, 8 waves, worklist): eact = silu(x@wg)*(x@wu) ----------------
__global__ __launch_bounds__(512)
void k_moe1m(const short* __restrict__ X, const short* __restrict__ WGt, const short* __restrict__ WUt,
             const int* __restrict__ ecnt, const int* __restrict__ etok,
             const int* __restrict__ wl, const int* __restrict__ wcnt,
             short* __restrict__ eact) {
    if ((int)blockIdx.x >= wcnt[0]) return;
    int ent = wl[blockIdx.x];
    int e = ent >> 20, base = ent & 0xFFFFF;
    int rows = min(128, ecnt[e] - base);
    int n0 = blockIdx.y * 64;
    __shared__ __align__(16) short As[128 * 64];
    __shared__ __align__(16) short Bg[64 * 64];
    __shared__ __align__(16) short Bu[64 * 64];
    __shared__ int toks[128];
    int tid = threadIdx.x;
    if (tid < 128) toks[tid] = (tid < rows) ? etok[e * 4096 + base + tid] : -1;
    __syncthreads();
    int w = tid >> 6, l = tid & 63, g = l >> 4, li = l & 15;
    int wm = w >> 1, wn = w & 1;     // wm 0..3, wn 0..1
    const short* wgp = WGt + (size_t)e * 256 * 512;
    const short* wup = WUt + (size_t)e * 256 * 512;
    f32x4 ag[2][2] = {}, au[2][2] = {};
    for (int k0 = 0; k0 < 512; k0 += 64) {
        __syncthreads();
#pragma unroll
        for (int p = 0; p < 2; ++p) {
            int flat = p * 512 + tid;
            int row = flat >> 3, ch = flat & 7;
            int tk = toks[row];
            int4 v = {0, 0, 0, 0};
            if (tk >= 0) v = *(const int4*)(X + (size_t)(tk >> 2) * 512 + k0 + 8 * ch);
            *(int4*)&As[row * 64 + ((ch ^ (row & 7)) * 8)] = v;
        }
        {
            int n = tid >> 3, ch = tid & 7;
            *(int4*)&Bg[n * 64 + ((ch ^ (n & 7)) * 8)] = *(const int4*)(wgp + (size_t)(n0 + n) * 512 + k0 + 8 * ch);
            *(int4*)&Bu[n * 64 + ((ch ^ (n & 7)) * 8)] = *(const int4*)(wup + (size_t)(n0 + n) * 512 + k0 + 8 * ch);
        }
        __syncthreads();
#pragma unroll
        for (int kc = 0; kc < 2; ++kc) {
            s16x8 af[2], bg[2], bu[2];
#pragma unroll
            for (int mt = 0; mt < 2; ++mt) {
                int row = wm * 32 + mt * 16 + li;
                af[mt] = *(const s16x8*)&As[row * 64 + (((4 * kc + g) ^ (li & 7)) * 8)];
            }
#pragma unroll
            for (int nt = 0; nt < 2; ++nt) {
                int n = wn * 32 + nt * 16 + li;
                bg[nt] = *(const s16x8*)&Bg[n * 64 + (((4 * kc + g) ^ (li & 7)) * 8)];
                bu[nt] = *(const s16x8*)&Bu[n * 64 + (((4 * kc + g) ^ (li & 7)) * 8)];
            }
#pragma unroll
            for (int mt = 0; mt < 2; ++mt)
#pragma unroll
                for (int nt = 0; nt < 2; ++nt) {
                    ag[mt][nt] = __builtin_amdgcn_mfma_f32_16x16x32_bf16(af[mt], bg[nt], ag[mt][nt], 0, 0, 0);
                    au[mt][nt] = __builtin_amdgcn_mfma_f32_16x16x32_bf16(af[mt], bu[nt], au[mt][nt], 0, 0, 0);
                }
        }
    }
#pragma unroll
    for (int mt = 0; mt < 2; ++mt)
#pragma unroll
        for (int nt = 0; nt < 2; ++nt)
#pragma unroll
            for (int r = 0; r < 4; ++r) {
                int local = wm * 32 + mt * 16 + 4 * g + r;
                if (local < rows) {
                    int entry = toks[local];
                    int gn = n0 + wn * 32 + nt * 16 + li;
                    float gv = ag[mt][nt][r], uv = au[mt][nt][r];
                    eact[(size_t)entry * 256 + gn] = f2b(gv / (1.f + __expf(-gv)) * uv);
                }
            }
}

// ---------------- MoE stage 2 (MFMA, 8 waves, worklist): out += w * (eact @ wd) ----------------
__global__ __launch_bounds__(512)
void k_moe2m(const short* __restrict__ EA, const short* __restrict__ WDt,
             const int* __restrict__ ecnt, const int* __restrict__ etok,
             const int* __restrict__ wl, const int* __restrict__ wcnt,
             const float* __restrict__ ewt, float* __restrict__ oacc) {
    if ((int)blockIdx.x >= wcnt[0]) return;
    int ent = wl[blockIdx.x];
    int e = ent >> 20, base = ent & 0xFFFFF;
    int rows = min(128, ecnt[e] - base);
    int n0 = blockIdx.y * 64;
    __shared__ __align__(16) short As[128 * 64];
    __shared__ __align__(16) short Bs[64 * 64];
    __shared__ int toks[128];
    __shared__ float wts[128];
    int tid = threadIdx.x;
    if (tid < 128) {
        toks[tid] = (tid < rows) ? etok[e * 4096 + base + tid] : -1;
        wts[tid]  = (tid < rows) ? ewt[e * 4096 + base + tid] : 0.f;
    }
    __syncthreads();
    int w = tid >> 6, l = tid & 63, g = l >> 4, li = l & 15;
    int wm = w >> 1, wn = w & 1;
    const short* wdp = WDt + (size_t)e * 512 * 256;
    f32x4 acc[2][2] = {};
    for (int k0 = 0; k0 < 256; k0 += 64) {
        __syncthreads();
#pragma unroll
        for (int p = 0; p < 2; ++p) {
            int flat = p * 512 + tid;
            int row = flat >> 3, ch = flat & 7;
            int tk = toks[row];
            int4 v = {0, 0, 0, 0};
            if (tk >= 0) v = *(const int4*)(EA + (size_t)tk * 256 + k0 + 8 * ch);
            *(int4*)&As[row * 64 + ((ch ^ (row & 7)) * 8)] = v;
        }
        {
            int n = tid >> 3, ch = tid & 7;
            *(int4*)&Bs[n * 64 + ((ch ^ (n & 7)) * 8)] = *(const int4*)(wdp + (size_t)(n0 + n) * 256 + k0 + 8 * ch);
        }
        __syncthreads();
#pragma unroll
        for (int kc = 0; kc < 2; ++kc) {
            s16x8 af[2], bf[2];
#pragma unroll
            for (int mt = 0; mt < 2; ++mt) {
                int row = wm * 32 + mt * 16 + li;
                af[mt] = *(const s16x8*)&As[row * 64 + (((4 * kc + g) ^ (li & 7)) * 8)];
            }
#pragma unroll
            for (int nt = 0; nt < 2; ++nt) {
                int n = wn * 32 + nt * 16 + li;
                bf[nt] = *(const s16x8*)&Bs[n * 64 + (((4 * kc + g) ^ (li & 7)) * 8)];
            }
#pragma unroll
            for (int mt = 0; mt < 2; ++mt)
#pragma unroll
                for (int nt = 0; nt < 2; ++nt)
                    acc[mt][nt] = __builtin_amdgcn_mfma_f32_16x16x32_bf16(af[mt], bf[nt], acc[mt][nt], 0, 0, 0);
        }
    }
#pragma unroll
    for (int mt = 0; mt < 2; ++mt)
#pragma unroll
        for (int nt = 0; nt < 2; ++nt)
#pragma unroll
            for (int r = 0; r < 4; ++r) {
                int local = wm * 32 + mt * 16 + 4 * g + r;
                if (local < rows) {
                    int tok = toks[local] >> 2;
                    int gn = n0 + wn * 32 + nt * 16 + li;
                    atomicAdd(&oacc[(size_t)tok * 512 + gn], acc[mt][nt][r] * wts[local]);
                }
            }
}

// ---------------- host launcher ----------------
extern "C" void kernel_launch(void* const* d_in, const int* in_sizes, int n_in,
                              void* d_out, int out_size, void* d_ws, size_t ws_size,
                              hipStream_t stream) {
    const float* hs       = (const float*)d_in[0];
    const float* w_innorm = (const float*)d_in[1];
    const float* w_dq     = (const float*)d_in[2];
    const float* w_qnorm  = (const float*)d_in[3];
    const float* w_uq     = (const float*)d_in[4];
    const float* w_dkv    = (const float*)d_in[5];
    const float* w_kvnorm = (const float*)d_in[6];
    const float* w_ukv    = (const float*)d_in[7];
    const float* w_o      = (const float*)d_in[8];
    const float* w_post   = (const float*)d_in[9];
    const float* w_gate   = (const float*)d_in[10];
    const float* sh_wg    = (const float*)d_in[11];
    const float* sh_wu    = (const float*)d_in[12];
    const float* sh_wd    = (const float*)d_in[13];
    const float* r_wg     = (const float*)d_in[14];
    const float* r_wu     = (const float*)d_in[15];
    const float* r_wd     = (const float*)d_in[16];

    float* ws   = (float*)d_ws;
    float* cq   = ws + OFF_CQ;
    float* ckv  = ws + OFF_CKV;
    float* qcr  = ws + OFF_QCR;
    float* kvb  = ws + OFF_KVB;
    float* r2   = ws + OFF_R2;
    float* xn2  = ws + OFF_XN2;
    int4*  toke = (int4*)(ws + OFF_TOKE);
    float4* tokw = (float4*)(ws + OFF_TOKW);
    float* ewt  = ws + OFF_EWT;
    int*   ecnt = (int*)(ws + OFF_ECNT);
    int*   etok = (int*)(ws + OFF_ETOK);
    int*   wl   = (int*)(ws + OFF_WL);
    int*   wcnt = (int*)(ws + OFF_WCNT);
    short* xnb   = (short*)(ws + OFF_XNB);
    short* cqnb  = (short*)(ws + OFF_CQNB);
    short* ckvnb = (short*)(ws + OFF_CKVNB);
    short* qb    = (short*)(ws + OFF_QB);
    short* kb    = (short*)(ws + OFF_KB);
    short* vbt   = (short*)(ws + OFF_VBT);
    short* aob   = (short*)(ws + OFF_AOB);
    short* xn2b  = (short*)(ws + OFF_XN2B);
    short* gact  = (short*)(ws + OFF_GACT);
    short* eact  = (short*)(ws + OFF_EACT);
    short* wdqT  = (short*)(ws + OFF_WDQT);
    short* wdkvT = (short*)(ws + OFF_WDKVT);
    short* wuqT  = (short*)(ws + OFF_WUQT);
    short* wukvT = (short*)(ws + OFF_WUKVT);
    short* woT   = (short*)(ws + OFF_WOT);
    short* shwgT = (short*)(ws + OFF_SHWGT);
    short* shwuT = (short*)(ws + OFF_SHWUT);
    short* shwdT = (short*)(ws + OFF_SHWDT);
    short* rwgT  = (short*)(ws + OFF_RWGT);
    short* rwuT  = (short*)(ws + OFF_RWUT);
    short* rwdT  = (short*)(ws + OFF_RWDT);

    float* outF = (float*)d_out;   // final accumulator lives directly in d_out

    // 0. weight convert+transpose (bf16 [N][K])
    k_cvt_t<<<dim3(8, 16, 1),  256, 0, stream>>>(w_dq,  wdqT,  512, 256);
    k_cvt_t<<<dim3(5, 16, 1),  256, 0, stream>>>(w_dkv, wdkvT, 512, 160);
    k_cvt_t<<<dim3(24, 8, 1),  256, 0, stream>>>(w_uq,  wuqT,  256, 768);
    k_cvt_t<<<dim3(32, 4, 1),  256, 0, stream>>>(w_ukv, wukvT, 128, 1024);
    k_cvt_t<<<dim3(16, 16, 1), 256, 0, stream>>>(w_o,   woT,   512, 512);
    k_cvt_t<<<dim3(8, 16, 1),  256, 0, stream>>>(sh_wg, shwgT, 512, 256);
    k_cvt_t<<<dim3(8, 16, 1),  256, 0, stream>>>(sh_wu, shwuT, 512, 256);
    k_cvt_t<<<dim3(16, 8, 1),  256, 0, stream>>>(sh_wd, shwdT, 256, 512);
    k_cvt_t<<<dim3(8, 16, 16), 256, 0, stream>>>(r_wg,  rwgT,  512, 256);
    k_cvt_t<<<dim3(8, 16, 16), 256, 0, stream>>>(r_wu,  rwuT,  512, 256);
    k_cvt_t<<<dim3(16, 8, 16), 256, 0, stream>>>(r_wd,  rwdT,  256, 512);

    // 1. input RMSNorm -> bf16
    k_rms<<<Tt, 256, 0, stream>>>(hs, 512, w_innorm, nullptr, xnb, 512, 512);
    // 2. down-projections
    k_mgemm<0><<<dim3(4, 64), 256, 0, stream>>>(xnb, wdqT, cq, nullptr, 256, 512);
    k_mgemm<0><<<dim3(3, 64), 256, 0, stream>>>(xnb, wdkvT, ckv, nullptr, 160, 512);
    // 3. latent norms -> bf16
    k_rms<<<Tt, 256, 0, stream>>>(cq, 256, w_qnorm, nullptr, cqnb, 256, 256);
    k_rms<<<Tt, 256, 0, stream>>>(ckv, 160, w_kvnorm, nullptr, ckvnb, 128, 128);
    // 4. up-projections
    k_mgemm<0><<<dim3(12, 64), 256, 0, stream>>>(cqnb, wuqT, qcr, nullptr, 768, 256);
    k_mgemm<0><<<dim3(16, 64), 256, 0, stream>>>(ckvnb, wukvT, kvb, nullptr, 1024, 128);
    // 5. build q/k/v (RoPE) -> bf16
    k_build_q<<<(16 * 2048 * 96) / 256, 256, 0, stream>>>(qcr, qb);
    k_build_k<<<(16 * 2048 * 96) / 256, 256, 0, stream>>>(kvb, ckv, kb);
    k_build_vt<<<(16 * 64 * 2048) / 256, 256, 0, stream>>>(kvb, vbt);
    // 6. MFMA flash attention
    k_attn<<<512, 256, 0, stream>>>(qb, kb, vbt, aob);
    // 7. output proj + residual
    k_mgemm<1><<<dim3(8, 64), 256, 0, stream>>>(aob, woT, r2, hs, 512, 512);
    // 8. post norm (f32 for router + bf16 for GEMMs)
    k_rms<<<Tt, 256, 0, stream>>>(r2, 512, w_post, xn2, xn2b, 512, 512);
    // 9. shared expert (fused dual-GEMM + swiglu) then down-proj + residual into d_out
    k_shexp<<<dim3(64, 4), 256, 0, stream>>>(xn2b, shwgT, shwuT, gact);
    k_mgemm<1><<<dim3(8, 64), 256, 0, stream>>>(gact, shwdT, outF, r2, 512, 256);
    // 10. router (no atomics) + block-aggregated scatter + worklist + MoE
    k_router<<<Tt / 4, 256, 0, stream>>>(xn2, w_gate, toke, tokw);
    hipMemsetAsync(ecnt, 0, NEn * sizeof(int), stream);
    k_scatter<<<16, 256, 0, stream>>>(toke, tokw, ewt, ecnt, etok);
    k_worklist<<<1, 64, 0, stream>>>(ecnt, wl, wcnt);
    k_moe1m<<<dim3(144, 4), 512, 0, stream>>>(xn2b, rwgT, rwuT, ecnt, etok, wl, wcnt, eact);
    k_moe2m<<<dim3(144, 8), 512, 0, stream>>>(eact, rwdT, ecnt, etok, wl, wcnt, ewt, outF);
}